// Round 5
// baseline (23745.419 us; speedup 1.0000x reference)
//
#include <hip/hip_runtime.h>
#include <hip/hip_bf16.h>
#include <cstdint>

#define RR 512          // B*K rows
#define KB_ 8           // beams
#define VV 400          // vocab
#define HD_ 1024
#define GD 4096         // 4*HD
#define LL 13           // program_len
#define NPTS 1000       // integration points
#define OUT_N 18560

// unordered pair tables (j<l) for the 28 off-diagonal logsumexp reductions
__device__ __constant__ int cPJ[28] = {0,0,0,0,0,0,0,1,1,1,1,1,1,2,2,2,2,2,3,3,3,3,4,4,4,5,5,6};
__device__ __constant__ int cPL[28] = {1,2,3,4,5,6,7,2,3,4,5,6,7,3,4,5,6,7,4,5,6,7,5,6,7,6,7,7};

__device__ __forceinline__ float r5_log1mexp(float x) {
  x = fminf(x, -1e-38f);
  return (x > -0.6931472f) ? logf(-expm1f(x)) : log1pf(-expf(x));
}

__device__ __forceinline__ float r5_sigm(float x) { return 1.f / (1.f + expf(-x)); }

__device__ __forceinline__ int r5_pidx(int j, int l) {
  if (j > l) { int t = j; j = l; l = t; }
  return 9 + (j * (15 - j)) / 2 + (l - j - 1);
}

// ---- block (256 threads = 4 waves) reductions ----
__device__ __forceinline__ float r5_bmax256(float v, float* red) {
  #pragma unroll
  for (int o = 32; o; o >>= 1) v = fmaxf(v, __shfl_xor(v, o, 64));
  __syncthreads();
  if ((threadIdx.x & 63) == 0) red[threadIdx.x >> 6] = v;
  __syncthreads();
  return fmaxf(fmaxf(red[0], red[1]), fmaxf(red[2], red[3]));
}

__device__ __forceinline__ float r5_bsum256(float v, float* red) {
  #pragma unroll
  for (int o = 32; o; o >>= 1) v += __shfl_xor(v, o, 64);
  __syncthreads();
  if ((threadIdx.x & 63) == 0) red[threadIdx.x >> 6] = v;
  __syncthreads();
  return (red[0] + red[1]) + (red[2] + red[3]);
}

// ---- zero the carried-state workspace pieces ----
__global__ __launch_bounds__(256) void r5_wszero(float* hb, float* cb, float* Gv,
                                                 float* logp0, float* accum) {
  int idx = blockIdx.x * 256 + threadIdx.x;
  if (idx < RR * HD_) { hb[idx] = 0.f; cb[idx] = 0.f; }
  if (idx < RR) { Gv[idx] = 0.f; logp0[idx] = 0.f; }
  if (idx < 128) accum[idx] = 0.f;
}

// ---- ws-too-small sentinel: float dout[6656] = 20000 (chunk-1 first elem) ----
__global__ __launch_bounds__(256) void r5_flag(float* dout) {
  int idx = blockIdx.x * 256 + threadIdx.x;
  if (idx < OUT_N) dout[idx] = (idx == 6656) ? 20000.0f : 0.0f;
}

// xfb[i, c] = x_feat[i,:1024] . W_ih[c,:1024] + b_ih[c] + b_hh[c]
__global__ __launch_bounds__(256) void r5_xfb(const float* __restrict__ xf,
                                              const float* __restrict__ Wih,
                                              const float* __restrict__ bih,
                                              const float* __restrict__ bhh,
                                              float* __restrict__ xfb) {
  int idx = blockIdx.x * 256 + threadIdx.x;   // 64*4096
  if (idx >= 64 * GD) return;
  int i = idx >> 12, c = idx & 4095;
  const float* xr = xf + (size_t)i * 1024;
  const float* wr = Wih + (size_t)c * 1152;
  float acc = 0.f;
  for (int k = 0; k < 1024; ++k) acc = fmaf(xr[k], wr[k], acc);
  xfb[idx] = acc + bih[c] + bhh[c];
}

// inp_op[r,m] = relu(W_in_op[m, s] + b_in_op[m])
__global__ __launch_bounds__(256) void r5_inp(const int* s_arr, int t, const float* Wio,
                                              const float* bio, float* inp) {
  int idx = blockIdx.x * 256 + threadIdx.x;   // 512*128
  int r = idx >> 7, m = idx & 127;
  int s = (t == 0) ? 400 : s_arr[(size_t)(t - 1) * RR + r];
  float v = Wio[m * 401 + s] + bio[m];
  inp[idx] = fmaxf(v, 0.f);
}

// gates[r, c] = xfb[r%64, c] + h[r,:].W_hh[c,:] + inp[r,:].W_ih[c,1024:]
__global__ __launch_bounds__(256) void r5_gates(const float* __restrict__ h,
                                                const float* __restrict__ inp,
                                                const float* __restrict__ Whh,
                                                const float* __restrict__ Wih,
                                                const float* __restrict__ xfb,
                                                float* __restrict__ gates) {
  int idx = blockIdx.x * 256 + threadIdx.x;   // 512*4096
  if (idx >= RR * GD) return;
  int r = idx >> 12, c = idx & 4095;
  const float* hr = h + (size_t)r * HD_;
  const float* wr = Whh + (size_t)c * HD_;
  float acc = 0.f;
  for (int k = 0; k < 1024; ++k) acc = fmaf(hr[k], wr[k], acc);
  const float* ir = inp + (size_t)r * 128;
  const float* w2 = Wih + (size_t)c * 1152 + 1024;
  for (int k = 0; k < 128; ++k) acc = fmaf(ir[k], w2[k], acc);
  gates[idx] = acc + xfb[(size_t)(r & 63) * GD + c];
}

// LSTM pointwise (torch gate order i,f,g,o)
__global__ __launch_bounds__(256) void r5_lstm(const float* gates, const float* cin,
                                               float* cout, float* hout) {
  int idx = blockIdx.x * 256 + threadIdx.x;   // 512*1024
  int r = idx >> 10, n = idx & 1023;
  const float* g = gates + (size_t)r * GD;
  float ig = r5_sigm(g[n]);
  float fg = r5_sigm(g[1024 + n]);
  float gg = tanhf(g[2048 + n]);
  float og = r5_sigm(g[3072 + n]);
  float c = fg * cin[idx] + ig * gg;
  cout[idx] = c;
  hout[idx] = og * tanhf(c);
}

// hd[r, c] = relu(h[r,:].W_fc1[c,:] + b_fc1[c])
__global__ __launch_bounds__(256) void r5_fc1(const float* __restrict__ h,
                                              const float* __restrict__ W1,
                                              const float* __restrict__ b1,
                                              float* __restrict__ hd) {
  int idx = blockIdx.x * 256 + threadIdx.x;   // 512*1024
  if (idx >= RR * HD_) return;
  int r = idx >> 10, c = idx & 1023;
  const float* hr = h + (size_t)r * HD_;
  const float* wr = W1 + (size_t)c * HD_;
  float acc = 0.f;
  for (int k = 0; k < 1024; ++k) acc = fmaf(hr[k], wr[k], acc);
  hd[idx] = fmaxf(acc + b1[c], 0.f);
}

// logits[r, v] = hd[r,:].W_out[v,:] + b_out[v]
__global__ __launch_bounds__(256) void r5_out(const float* __restrict__ hd,
                                              const float* __restrict__ Wo,
                                              const float* __restrict__ bo,
                                              float* __restrict__ logits) {
  int idx = blockIdx.x * 256 + threadIdx.x;   // 512*400
  if (idx >= RR * VV) return;
  int r = idx / VV, v = idx % VV;
  const float* hr = hd + (size_t)r * HD_;
  const float* wr = Wo + (size_t)v * HD_;
  float acc = 0.f;
  for (int k = 0; k < 1024; ++k) acc = fmaf(hr[k], wr[k], acc);
  logits[idx] = acc + bo[v];
}

// per-row: log_softmax, entropy, gumbel-with-max; write lp + beams-layout g
__global__ __launch_bounds__(256) void r5_soft(const float* logits, const float* logp_in,
                                               const float* Gv, const float* gum,
                                               float* lp, float* gb, float* entold) {
  __shared__ float red[4];
  int r = blockIdx.x, tid = threadIdx.x;
  const float* lr = logits + (size_t)r * VV;
  bool v1 = (tid + 256) < VV;
  float l0 = lr[tid];
  float l1 = v1 ? lr[tid + 256] : -INFINITY;
  float m = r5_bmax256(fmaxf(l0, l1), red);
  float e0 = expf(l0 - m), e1 = v1 ? expf(l1 - m) : 0.f;
  float s = r5_bsum256(e0 + e1, red);
  float ls = logf(s);
  float lp0 = l0 - m - ls, lp1 = l1 - m - ls;
  float ent = lp0 * expf(lp0) + (v1 ? lp1 * expf(lp1) : 0.f);
  ent = r5_bsum256(ent, red);
  if (tid == 0) entold[r] = ent;
  float lpr = logp_in[r];
  const float* ur = gum + (size_t)r * VV;
  float gp0, gp1 = -INFINITY;
  { float u = ur[tid];
    gp0 = lp0 + lpr - logf(-logf(u * (1.f - 2e-7f) + 1e-7f)); }
  if (v1) { float u = ur[tid + 256];
            gp1 = lp1 + lpr - logf(-logf(u * (1.f - 2e-7f) + 1e-7f)); }
  float Z = r5_bmax256(fmaxf(gp0, gp1), red);
  float T = Gv[r];
  int i = r & 63, j = r >> 6;
  float* gbr = gb + (size_t)i * (KB_ * VV) + j * VV;
  {
    float vv = T - gp0 + r5_log1mexp(gp0 - Z);
    gbr[tid] = T - fmaxf(vv, 0.f) - log1pf(expf(-fabsf(vv)));
    lp[(size_t)r * VV + tid] = lp0;
  }
  if (v1) {
    float vv = T - gp1 + r5_log1mexp(gp1 - Z);
    gbr[tid + 256] = T - fmaxf(vv, 0.f) - log1pf(expf(-fabsf(vv)));
    lp[(size_t)r * VV + tid + 256] = lp1;
  }
}

// per-batch top-8 (tie -> lower flat index), emit G / sample / parent
__global__ __launch_bounds__(256) void r5_topk(const float* gb, int t, float* Gv,
                                               int* s_t, int* o_t) {
  __shared__ float vals[KB_ * VV];
  __shared__ float rv[256];
  __shared__ int ri[256];
  int i = blockIdx.x, tid = threadIdx.x;
  int limit = (t == 0) ? VV : KB_ * VV;
  for (int c = tid; c < limit; c += 256) vals[c] = gb[(size_t)i * (KB_ * VV) + c];
  __syncthreads();
  for (int it = 0; it < KB_; ++it) {
    float bv = -INFINITY; int bi = 0x7fffffff;
    for (int c = tid; c < limit; c += 256) {
      float v = vals[c];
      if (v > bv || (v == bv && c < bi)) { bv = v; bi = c; }
    }
    rv[tid] = bv; ri[tid] = bi;
    __syncthreads();
    for (int s2 = 128; s2; s2 >>= 1) {
      if (tid < s2) {
        float v2 = rv[tid + s2]; int i2 = ri[tid + s2];
        if (v2 > rv[tid] || (v2 == rv[tid] && i2 < ri[tid])) { rv[tid] = v2; ri[tid] = i2; }
      }
      __syncthreads();
    }
    if (tid == 0) {
      int r = it * 64 + i;
      Gv[r] = rv[0];
      s_t[r] = ri[0] % VV;
      o_t[r] = (ri[0] / VV) * 64 + i;
      vals[ri[0]] = -INFINITY;
    }
    __syncthreads();
  }
}

// gather h,c by parent order
__global__ __launch_bounds__(256) void r5_rb(const float* ht, const float* ct,
                                             const int* o_t, float* ho, float* co) {
  int idx = blockIdx.x * 256 + threadIdx.x;   // 512*1024
  int r = idx >> 10, n = idx & 1023;
  int src = (o_t[r] << 10) | n;
  ho[idx] = ht[src];
  co[idx] = ct[src];
}

// per-row scalar updates: logp, entbm, lv record
__global__ __launch_bounds__(512) void r5_sel(const float* lp, const int* o_t, const int* s_t,
                                              const float* logp_in, float* logp_out,
                                              const float* entold, float* entbm,
                                              float* lv_t) {
  int r = threadIdx.x;   // 512
  int o = o_t[r], s = s_t[r];
  float lv = lp[(size_t)o * VV + s];
  logp_out[r] = logp_in[o] + lv;
  entbm[r] = entold[o];
  lv_t[r] = lv;
}

// compute_log_R per batch + entropy accumulation (+ final-step outputs, float32)
__global__ __launch_bounds__(256) void r5_logR(const float* logp_new, const float* entbm,
                                               float* accum, float* dout, int last) {
  __shared__ float Tm[KB_][NPTS];
  __shared__ float base[NPTS];
  __shared__ float red[4];
  __shared__ float phi[KB_], pj[KB_];
  __shared__ float res[37];
  int i = blockIdx.x, tid = threadIdx.x;
  if (tid < KB_) { float ph = logp_new[tid * 64 + i]; phi[tid] = ph; pj[tid] = expf(ph); }
  __syncthreads();
  float pS = ((pj[0] + pj[1]) + (pj[2] + pj[3])) + ((pj[4] + pj[5]) + (pj[6] + pj[7]));
  for (int n = tid; n < NPTS; n += 256) {
    float lu = logf((n + 0.5f) * (1.0f / NPTS));
    float b = -pS * lu;
    #pragma unroll
    for (int j = 0; j < KB_; ++j) {
      float tv = r5_log1mexp(pj[j] * lu);
      Tm[j][n] = tv; b += tv;
    }
    base[n] = b;
  }
  __syncthreads();
  const float logN = 6.9077552789821f;   // log(1000)
  for (int ridx = 0; ridx < 37; ++ridx) {
    int jj = -1, ll = -1;
    if (ridx >= 1 && ridx < 9) jj = ridx - 1;
    else if (ridx >= 9) { jj = cPJ[ridx - 9]; ll = cPL[ridx - 9]; }
    float mx = -INFINITY;
    for (int n = tid; n < NPTS; n += 256) {
      float v = base[n];
      if (jj >= 0) v -= Tm[jj][n];
      if (ll >= 0) v -= Tm[ll][n];
      mx = fmaxf(mx, v);
    }
    mx = r5_bmax256(mx, red);
    float sm = 0.f;
    for (int n = tid; n < NPTS; n += 256) {
      float v = base[n];
      if (jj >= 0) v -= Tm[jj][n];
      if (ll >= 0) v -= Tm[ll][n];
      sm += expf(v - mx);
    }
    sm = r5_bsum256(sm, red);
    if (tid == 0) res[ridx] = mx + logf(sm) - logN;
    __syncthreads();
  }
  if (tid == 0) {
    float logI = res[0];
    float Wsum = 0.f, ws = 0.f;
    #pragma unroll
    for (int j = 0; j < KB_; ++j) {
      float lRs = res[1 + j] - logI;
      float wj = expf(phi[j] + lRs);
      Wsum += wj;
      ws += wj * entbm[j * 64 + i];
    }
    accum[i] += ws;               // ent_plot
    accum[64 + i] += ws / Wsum;   // entropy_element
    if (last) {
      for (int j = 0; j < KB_; ++j) {
        dout[13376 + i * 8 + j] = res[1 + j] - logI;     // log_R_s
        dout[17984 + i * 8 + j] = phi[j];                // phi_k
        for (int l = 0; l < KB_; ++l) {
          float v = (l == j) ? 0.f : (res[r5_pidx(j, l)] - res[1 + j]);
          dout[13888 + i * 64 + j * 8 + l] = v;          // log_R_ss
        }
      }
    }
  }
}

// final: walk ancestor chains to rebuild histories, pack all outputs (float32)
__global__ __launch_bounds__(512) void r5_final(const float* lv_arr, const int* s_arr,
                                                const int* o_arr, const float* accum,
                                                float* dout) {
  int r = threadIdx.x;   // one thread per final beam row (beam-major j*64+i)
  int i = r & 63, j = r >> 6;
  float vals[LL]; int svs[LL];
  int a = r;
  for (int tt = LL - 1; tt >= 0; --tt) {
    vals[tt] = lv_arr[tt * RR + a];
    svs[tt]  = s_arr[tt * RR + a];
    a = o_arr[tt * RR + a];
  }
  #pragma unroll
  for (int tt = 0; tt < LL; ++tt) {
    dout[i * 104 + j * 13 + tt] = vals[tt];               // outputs
    dout[6656 + i * 104 + j * 13 + tt] = (float)svs[tt];  // samples
  }
  if (r < 64) {
    dout[13312 + r] = accum[64 + r];   // entropy_element
    dout[18496 + r] = accum[r];        // ent_plot
  }
}

extern "C" void kernel_launch(void* const* d_in, const int* in_sizes, int n_in,
                              void* d_out, int out_size, void* d_ws, size_t ws_size,
                              hipStream_t stream) {
  const float* x_feat  = (const float*)d_in[0];
  const float* W_in_op = (const float*)d_in[1];
  const float* b_in_op = (const float*)d_in[2];
  const float* W_ih    = (const float*)d_in[3];
  const float* W_hh    = (const float*)d_in[4];
  const float* b_ih    = (const float*)d_in[5];
  const float* b_hh    = (const float*)d_in[6];
  const float* W_fc1   = (const float*)d_in[7];
  const float* b_fc1   = (const float*)d_in[8];
  const float* W_out   = (const float*)d_in[9];
  const float* b_out   = (const float*)d_in[10];
  const float* gum     = (const float*)d_in[11];
  float* out           = (float*)d_out;     // <-- float32 output (round-4 finding)

  float* W = (float*)d_ws;
  size_t o = 0;
  float* lv_arr = W + o; o += (size_t)LL * RR;
  float* Gv     = W + o; o += RR;
  float* logpb0 = W + o; o += RR;
  float* logpb1 = W + o; o += RR;
  float* entold = W + o; o += RR;
  float* entbm  = W + o; o += RR;
  float* accum  = W + o; o += 128;
  int* s_arr = (int*)(W + o); o += (size_t)LL * RR;
  int* o_arr = (int*)(W + o); o += (size_t)LL * RR;
  float* xfb    = W + o; o += (size_t)64 * GD;
  float* inp    = W + o; o += (size_t)RR * 128;
  float* gates  = W + o; o += (size_t)RR * GD;
  float* logits = W + o; o += (size_t)RR * VV;
  float* lp     = W + o; o += (size_t)RR * VV;
  float* gb     = W + o; o += (size_t)RR * VV;
  float* hb     = W + o; o += (size_t)RR * HD_;
  float* cb     = W + o; o += (size_t)RR * HD_;
  float* htmp   = W + o; o += (size_t)RR * HD_;
  float* ctmp   = W + o; o += (size_t)RR * HD_;
  float* hd     = W + o; o += (size_t)RR * HD_;
  size_t needed_bytes = o * sizeof(float);
  float* logpb[2] = {logpb0, logpb1};

  if (ws_size < needed_bytes) {
    r5_flag<<<(OUT_N + 255) / 256, 256, 0, stream>>>(out);
    return;
  }

  r5_wszero<<<2048, 256, 0, stream>>>(hb, cb, Gv, logpb[0], accum);
  r5_xfb<<<(64 * GD + 255) / 256, 256, 0, stream>>>(x_feat, W_ih, b_ih, b_hh, xfb);

  for (int t = 0; t < LL; ++t) {
    int pi = t & 1, po = pi ^ 1;
    r5_inp<<<256, 256, 0, stream>>>(s_arr, t, W_in_op, b_in_op, inp);
    r5_gates<<<(RR * GD + 255) / 256, 256, 0, stream>>>(hb, inp, W_hh, W_ih, xfb, gates);
    r5_lstm<<<2048, 256, 0, stream>>>(gates, cb, ctmp, htmp);
    r5_fc1<<<(RR * HD_ + 255) / 256, 256, 0, stream>>>(htmp, W_fc1, b_fc1, hd);
    r5_out<<<(RR * VV + 255) / 256, 256, 0, stream>>>(hd, W_out, b_out, logits);
    r5_soft<<<512, 256, 0, stream>>>(logits, logpb[pi], Gv,
                                     gum + (size_t)t * RR * VV, lp, gb, entold);
    r5_topk<<<64, 256, 0, stream>>>(gb, t, Gv, s_arr + (size_t)t * RR,
                                    o_arr + (size_t)t * RR);
    r5_rb<<<2048, 256, 0, stream>>>(htmp, ctmp, o_arr + (size_t)t * RR, hb, cb);
    r5_sel<<<1, 512, 0, stream>>>(lp, o_arr + (size_t)t * RR, s_arr + (size_t)t * RR,
                                  logpb[pi], logpb[po], entold, entbm,
                                  lv_arr + (size_t)t * RR);
    r5_logR<<<64, 256, 0, stream>>>(logpb[po], entbm, accum, out, (t == LL - 1) ? 1 : 0);
  }
  r5_final<<<1, 512, 0, stream>>>(lv_arr, s_arr, o_arr, accum, out);
}

// Round 6
// 5194.096 us; speedup vs baseline: 4.5716x; 4.5716x over previous
//
#include <hip/hip_runtime.h>
#include <hip/hip_bf16.h>
#include <cstdint>

#define RR 512          // B*K rows
#define KB_ 8           // beams
#define VV 400          // vocab
#define HD_ 1024
#define GD 4096         // 4*HD
#define LL 13           // program_len
#define BKT 16          // GEMM K-tile
#define NPTS 1000       // integration points
#define OUT_N 18560

// unordered pair tables (j<l) for the 28 off-diagonal logsumexp reductions
__device__ __constant__ int cPJ[28] = {0,0,0,0,0,0,0,1,1,1,1,1,1,2,2,2,2,2,3,3,3,3,4,4,4,5,5,6};
__device__ __constant__ int cPL[28] = {1,2,3,4,5,6,7,2,3,4,5,6,7,3,4,5,6,7,4,5,6,7,5,6,7,6,7,7};

__device__ __forceinline__ float r6_log1mexp(float x) {
  x = fminf(x, -1e-38f);
  return (x > -0.6931472f) ? logf(-expm1f(x)) : log1pf(-expf(x));
}

__device__ __forceinline__ float r6_sigm(float x) { return 1.f / (1.f + expf(-x)); }

__device__ __forceinline__ int r6_pidx(int j, int l) {
  if (j > l) { int t = j; j = l; l = t; }
  return 9 + (j * (15 - j)) / 2 + (l - j - 1);
}

// ---- block (256 threads = 4 waves) reductions ----
__device__ __forceinline__ float r6_bmax256(float v, float* red) {
  #pragma unroll
  for (int o = 32; o; o >>= 1) v = fmaxf(v, __shfl_xor(v, o, 64));
  __syncthreads();
  if ((threadIdx.x & 63) == 0) red[threadIdx.x >> 6] = v;
  __syncthreads();
  return fmaxf(fmaxf(red[0], red[1]), fmaxf(red[2], red[3]));
}

__device__ __forceinline__ float r6_bsum256(float v, float* red) {
  #pragma unroll
  for (int o = 32; o; o >>= 1) v += __shfl_xor(v, o, 64);
  __syncthreads();
  if ((threadIdx.x & 63) == 0) red[threadIdx.x >> 6] = v;
  __syncthreads();
  return (red[0] + red[1]) + (red[2] + red[3]);
}

// ---- fp32 tiled GEMM core: C(64x64 tile) += A[r0.., :K] * W[n0.., :K]^T ----
// A row-major lda, W row-major ldw (weight rows = output cols). As/Bs: [BKT][64].
__device__ __forceinline__ void r6_gemm(
    const float* __restrict__ A, int lda,
    const float* __restrict__ W, int ldw,
    int K, int r0, int n0, int nmax,
    float (&acc)[4][4], float (*As)[64], float (*Bs)[64])
{
  const int tid = threadIdx.x;
  const int la = tid >> 2;          // 0..63
  const int lk = (tid & 3) << 2;    // 0,4,8,12
  const int tx = tid & 15, ty = tid >> 4;
  for (int k0 = 0; k0 < K; k0 += BKT) {
    float4 av = *reinterpret_cast<const float4*>(A + (size_t)(r0 + la) * lda + (k0 + lk));
    float4 bv = make_float4(0.f, 0.f, 0.f, 0.f);
    if (n0 + la < nmax)
      bv = *reinterpret_cast<const float4*>(W + (size_t)(n0 + la) * ldw + (k0 + lk));
    __syncthreads();   // previous tile's LDS reads complete
    As[lk + 0][la] = av.x; As[lk + 1][la] = av.y; As[lk + 2][la] = av.z; As[lk + 3][la] = av.w;
    Bs[lk + 0][la] = bv.x; Bs[lk + 1][la] = bv.y; Bs[lk + 2][la] = bv.z; Bs[lk + 3][la] = bv.w;
    __syncthreads();
    #pragma unroll
    for (int kk = 0; kk < BKT; ++kk) {
      float4 a = *reinterpret_cast<const float4*>(&As[kk][ty * 4]);
      float4 b = *reinterpret_cast<const float4*>(&Bs[kk][tx * 4]);
      float ar[4] = {a.x, a.y, a.z, a.w};
      float br[4] = {b.x, b.y, b.z, b.w};
      #pragma unroll
      for (int i = 0; i < 4; ++i)
        #pragma unroll
        for (int j = 0; j < 4; ++j)
          acc[i][j] = fmaf(ar[i], br[j], acc[i][j]);
    }
  }
}

// ---- 4-gate GEMM: acc[g] += A[r0..,:K] * W[g*1024+n0..,:K]^T for g=0..3 ----
__device__ __forceinline__ void r6_gemm4(
    const float* __restrict__ A, int lda,
    const float* __restrict__ W, int ldw,
    int K, int r0, int n0,
    float (&acc)[4][4][4], float (*As)[64], float (*Bs4)[BKT][64])
{
  const int tid = threadIdx.x;
  const int la = tid >> 2;
  const int lk = (tid & 3) << 2;
  const int tx = tid & 15, ty = tid >> 4;
  for (int k0 = 0; k0 < K; k0 += BKT) {
    float4 av = *reinterpret_cast<const float4*>(A + (size_t)(r0 + la) * lda + (k0 + lk));
    float4 bv[4];
    #pragma unroll
    for (int g = 0; g < 4; ++g)
      bv[g] = *reinterpret_cast<const float4*>(W + (size_t)(g * 1024 + n0 + la) * ldw + (k0 + lk));
    __syncthreads();
    As[lk + 0][la] = av.x; As[lk + 1][la] = av.y; As[lk + 2][la] = av.z; As[lk + 3][la] = av.w;
    #pragma unroll
    for (int g = 0; g < 4; ++g) {
      Bs4[g][lk + 0][la] = bv[g].x; Bs4[g][lk + 1][la] = bv[g].y;
      Bs4[g][lk + 2][la] = bv[g].z; Bs4[g][lk + 3][la] = bv[g].w;
    }
    __syncthreads();
    #pragma unroll
    for (int kk = 0; kk < BKT; ++kk) {
      float4 a = *reinterpret_cast<const float4*>(&As[kk][ty * 4]);
      float ar[4] = {a.x, a.y, a.z, a.w};
      #pragma unroll
      for (int g = 0; g < 4; ++g) {
        float4 b = *reinterpret_cast<const float4*>(&Bs4[g][kk][tx * 4]);
        float br[4] = {b.x, b.y, b.z, b.w};
        #pragma unroll
        for (int i = 0; i < 4; ++i)
          #pragma unroll
          for (int j = 0; j < 4; ++j)
            acc[g][i][j] = fmaf(ar[i], br[j], acc[g][i][j]);
      }
    }
  }
}

// ---- zero the carried-state workspace pieces ----
__global__ __launch_bounds__(256) void r6_wszero(float* hb, float* cb, float* Gv,
                                                 float* logp0, float* accum) {
  int idx = blockIdx.x * 256 + threadIdx.x;
  if (idx < RR * HD_) { hb[idx] = 0.f; cb[idx] = 0.f; }
  if (idx < RR) { Gv[idx] = 0.f; logp0[idx] = 0.f; }
  if (idx < 128) accum[idx] = 0.f;
}

// ---- ws-too-small sentinel ----
__global__ __launch_bounds__(256) void r6_flag(float* dout) {
  int idx = blockIdx.x * 256 + threadIdx.x;
  if (idx < OUT_N) dout[idx] = (idx == 6656) ? 20000.0f : 0.0f;
}

// xfb[i, c] = x_feat[i,:1024] . W_ih[c,:1024] + b_ih[c] + b_hh[c]  (once)
__global__ __launch_bounds__(256) void r6_xfb(const float* __restrict__ xf,
                                              const float* __restrict__ Wih,
                                              const float* __restrict__ bih,
                                              const float* __restrict__ bhh,
                                              float* __restrict__ xfb) {
  __shared__ __align__(16) float As[BKT][64];
  __shared__ __align__(16) float Bs[BKT][64];
  float acc[4][4] = {};
  int n0 = blockIdx.x * 64;
  r6_gemm(xf, 1024, Wih, 1152, 1024, 0, n0, 1 << 30, acc, As, Bs);
  int tx = threadIdx.x & 15, ty = threadIdx.x >> 4;
  #pragma unroll
  for (int i = 0; i < 4; ++i)
    #pragma unroll
    for (int j = 0; j < 4; ++j) {
      int r = ty * 4 + i, c = n0 + tx * 4 + j;
      xfb[(size_t)r * GD + c] = acc[i][j] + bih[c] + bhh[c];
    }
}

// inp_op[r,m] = relu(W_in_op[m, s] + b_in_op[m])
__global__ __launch_bounds__(256) void r6_inp(const int* s_arr, int t, const float* Wio,
                                              const float* bio, float* inp) {
  int idx = blockIdx.x * 256 + threadIdx.x;   // 512*128
  int r = idx >> 7, m = idx & 127;
  int s = (t == 0) ? 400 : s_arr[(size_t)(t - 1) * RR + r];
  float v = Wio[m * 401 + s] + bio[m];
  inp[idx] = fmaxf(v, 0.f);
}

// fused: gates = xfb + h@W_hh^T + inp@W_ih[:,1024:]^T, then LSTM pointwise
__global__ __launch_bounds__(256) void r6_glstm(const float* h, const float* inp,
                                                const float* Whh, const float* Wih,
                                                const float* xfb, const float* cin,
                                                float* cout, float* hout) {
  __shared__ __align__(16) float As[BKT][64];
  __shared__ __align__(16) float Bs4[4][BKT][64];
  float acc[4][4][4] = {};
  int n0 = blockIdx.x * 64, r0 = blockIdx.y * 64;
  r6_gemm4(h, HD_, Whh, HD_, HD_, r0, n0, acc, As, Bs4);
  r6_gemm4(inp, 128, Wih + 1024, 1152, 128, r0, n0, acc, As, Bs4);
  int tx = threadIdx.x & 15, ty = threadIdx.x >> 4;
  #pragma unroll
  for (int i = 0; i < 4; ++i) {
    int row = r0 + ty * 4 + i, rl = ty * 4 + i;   // rl = batch index (row % 64)
    #pragma unroll
    for (int j = 0; j < 4; ++j) {
      int col = n0 + tx * 4 + j;
      float gi = acc[0][i][j] + xfb[(size_t)rl * GD + col];
      float gf = acc[1][i][j] + xfb[(size_t)rl * GD + 1024 + col];
      float gg = acc[2][i][j] + xfb[(size_t)rl * GD + 2048 + col];
      float go = acc[3][i][j] + xfb[(size_t)rl * GD + 3072 + col];
      float cp = cin[(size_t)row * HD_ + col];
      float c = r6_sigm(gf) * cp + r6_sigm(gi) * tanhf(gg);
      cout[(size_t)row * HD_ + col] = c;
      hout[(size_t)row * HD_ + col] = r6_sigm(go) * tanhf(c);
    }
  }
}

// hd = relu(h @ W_fc1^T + b_fc1)
__global__ __launch_bounds__(256) void r6_fc1(const float* h, const float* W1,
                                              const float* b1, float* hd) {
  __shared__ __align__(16) float As[BKT][64];
  __shared__ __align__(16) float Bs[BKT][64];
  float acc[4][4] = {};
  int n0 = blockIdx.x * 64, r0 = blockIdx.y * 64;
  r6_gemm(h, HD_, W1, HD_, HD_, r0, n0, 1 << 30, acc, As, Bs);
  int tx = threadIdx.x & 15, ty = threadIdx.x >> 4;
  #pragma unroll
  for (int i = 0; i < 4; ++i)
    #pragma unroll
    for (int j = 0; j < 4; ++j) {
      int c = n0 + tx * 4 + j;
      hd[(size_t)(r0 + ty * 4 + i) * HD_ + c] = fmaxf(acc[i][j] + b1[c], 0.f);
    }
}

// logits = hd @ W_out^T + b_out (N=400, guarded)
__global__ __launch_bounds__(256) void r6_out(const float* hd, const float* Wo,
                                              const float* bo, float* logits) {
  __shared__ __align__(16) float As[BKT][64];
  __shared__ __align__(16) float Bs[BKT][64];
  float acc[4][4] = {};
  int n0 = blockIdx.x * 64, r0 = blockIdx.y * 64;
  r6_gemm(hd, HD_, Wo, HD_, HD_, r0, n0, VV, acc, As, Bs);
  int tx = threadIdx.x & 15, ty = threadIdx.x >> 4;
  #pragma unroll
  for (int i = 0; i < 4; ++i)
    #pragma unroll
    for (int j = 0; j < 4; ++j) {
      int c = n0 + tx * 4 + j;
      if (c < VV)
        logits[(size_t)(r0 + ty * 4 + i) * VV + c] = acc[i][j] + bo[c];
    }
}

// per-row: log_softmax, entropy, gumbel-with-max; write lp + beams-layout g
__global__ __launch_bounds__(256) void r6_soft(const float* logits, const float* logp_in,
                                               const float* Gv, const float* gum,
                                               float* lp, float* gb, float* entold) {
  __shared__ float red[4];
  int r = blockIdx.x, tid = threadIdx.x;
  const float* lr = logits + (size_t)r * VV;
  bool v1 = (tid + 256) < VV;
  float l0 = lr[tid];
  float l1 = v1 ? lr[tid + 256] : -INFINITY;
  float m = r6_bmax256(fmaxf(l0, l1), red);
  float e0 = expf(l0 - m), e1 = v1 ? expf(l1 - m) : 0.f;
  float s = r6_bsum256(e0 + e1, red);
  float ls = logf(s);
  float lp0 = l0 - m - ls, lp1 = l1 - m - ls;
  float ent = lp0 * expf(lp0) + (v1 ? lp1 * expf(lp1) : 0.f);
  ent = r6_bsum256(ent, red);
  if (tid == 0) entold[r] = ent;
  float lpr = logp_in[r];
  const float* ur = gum + (size_t)r * VV;
  float gp0, gp1 = -INFINITY;
  { float u = ur[tid];
    gp0 = lp0 + lpr - logf(-logf(u * (1.f - 2e-7f) + 1e-7f)); }
  if (v1) { float u = ur[tid + 256];
            gp1 = lp1 + lpr - logf(-logf(u * (1.f - 2e-7f) + 1e-7f)); }
  float Z = r6_bmax256(fmaxf(gp0, gp1), red);
  float T = Gv[r];
  int i = r & 63, j = r >> 6;
  float* gbr = gb + (size_t)i * (KB_ * VV) + j * VV;
  {
    float vv = T - gp0 + r6_log1mexp(gp0 - Z);
    gbr[tid] = T - fmaxf(vv, 0.f) - log1pf(expf(-fabsf(vv)));
    lp[(size_t)r * VV + tid] = lp0;
  }
  if (v1) {
    float vv = T - gp1 + r6_log1mexp(gp1 - Z);
    gbr[tid + 256] = T - fmaxf(vv, 0.f) - log1pf(expf(-fabsf(vv)));
    lp[(size_t)r * VV + tid + 256] = lp1;
  }
}

// per-batch top-8 (tie -> lower flat index), emit G / sample / parent
__global__ __launch_bounds__(256) void r6_topk(const float* gb, int t, float* Gv,
                                               int* s_t, int* o_t) {
  __shared__ float vals[KB_ * VV];
  __shared__ float rv[256];
  __shared__ int ri[256];
  int i = blockIdx.x, tid = threadIdx.x;
  int limit = (t == 0) ? VV : KB_ * VV;
  for (int c = tid; c < limit; c += 256) vals[c] = gb[(size_t)i * (KB_ * VV) + c];
  __syncthreads();
  for (int it = 0; it < KB_; ++it) {
    float bv = -INFINITY; int bi = 0x7fffffff;
    for (int c = tid; c < limit; c += 256) {
      float v = vals[c];
      if (v > bv || (v == bv && c < bi)) { bv = v; bi = c; }
    }
    rv[tid] = bv; ri[tid] = bi;
    __syncthreads();
    for (int s2 = 128; s2; s2 >>= 1) {
      if (tid < s2) {
        float v2 = rv[tid + s2]; int i2 = ri[tid + s2];
        if (v2 > rv[tid] || (v2 == rv[tid] && i2 < ri[tid])) { rv[tid] = v2; ri[tid] = i2; }
      }
      __syncthreads();
    }
    if (tid == 0) {
      int r = it * 64 + i;
      Gv[r] = rv[0];
      s_t[r] = ri[0] % VV;
      o_t[r] = (ri[0] / VV) * 64 + i;
      vals[ri[0]] = -INFINITY;
    }
    __syncthreads();
  }
}

// gather h,c by parent order
__global__ __launch_bounds__(256) void r6_rb(const float* ht, const float* ct,
                                             const int* o_t, float* ho, float* co) {
  int idx = blockIdx.x * 256 + threadIdx.x;   // 512*1024
  int r = idx >> 10, n = idx & 1023;
  int src = (o_t[r] << 10) | n;
  ho[idx] = ht[src];
  co[idx] = ct[src];
}

// per-row scalar updates: logp, entbm, lv record
__global__ __launch_bounds__(512) void r6_sel(const float* lp, const int* o_t, const int* s_t,
                                              const float* logp_in, float* logp_out,
                                              const float* entold, float* entbm,
                                              float* lv_t) {
  int r = threadIdx.x;   // 512
  int o = o_t[r], s = s_t[r];
  float lv = lp[(size_t)o * VV + s];
  logp_out[r] = logp_in[o] + lv;
  entbm[r] = entold[o];
  lv_t[r] = lv;
}

// compute_log_R per batch + entropy accumulation (+ final-step outputs, float32)
__global__ __launch_bounds__(256) void r6_logR(const float* logp_new, const float* entbm,
                                               float* accum, float* dout, int last) {
  __shared__ float Tm[KB_][NPTS];
  __shared__ float base[NPTS];
  __shared__ float red[4];
  __shared__ float phi[KB_], pj[KB_];
  __shared__ float res[37];
  int i = blockIdx.x, tid = threadIdx.x;
  if (tid < KB_) { float ph = logp_new[tid * 64 + i]; phi[tid] = ph; pj[tid] = expf(ph); }
  __syncthreads();
  float pS = ((pj[0] + pj[1]) + (pj[2] + pj[3])) + ((pj[4] + pj[5]) + (pj[6] + pj[7]));
  for (int n = tid; n < NPTS; n += 256) {
    float lu = logf((n + 0.5f) * (1.0f / NPTS));
    float b = -pS * lu;
    #pragma unroll
    for (int j = 0; j < KB_; ++j) {
      float tv = r6_log1mexp(pj[j] * lu);
      Tm[j][n] = tv; b += tv;
    }
    base[n] = b;
  }
  __syncthreads();
  const float logN = 6.9077552789821f;   // log(1000)
  for (int ridx = 0; ridx < 37; ++ridx) {
    int jj = -1, ll = -1;
    if (ridx >= 1 && ridx < 9) jj = ridx - 1;
    else if (ridx >= 9) { jj = cPJ[ridx - 9]; ll = cPL[ridx - 9]; }
    float mx = -INFINITY;
    for (int n = tid; n < NPTS; n += 256) {
      float v = base[n];
      if (jj >= 0) v -= Tm[jj][n];
      if (ll >= 0) v -= Tm[ll][n];
      mx = fmaxf(mx, v);
    }
    mx = r6_bmax256(mx, red);
    float sm = 0.f;
    for (int n = tid; n < NPTS; n += 256) {
      float v = base[n];
      if (jj >= 0) v -= Tm[jj][n];
      if (ll >= 0) v -= Tm[ll][n];
      sm += expf(v - mx);
    }
    sm = r6_bsum256(sm, red);
    if (tid == 0) res[ridx] = mx + logf(sm) - logN;
    __syncthreads();
  }
  if (tid == 0) {
    float logI = res[0];
    float Wsum = 0.f, ws = 0.f;
    #pragma unroll
    for (int j = 0; j < KB_; ++j) {
      float lRs = res[1 + j] - logI;
      float wj = expf(phi[j] + lRs);
      Wsum += wj;
      ws += wj * entbm[j * 64 + i];
    }
    accum[i] += ws;               // ent_plot
    accum[64 + i] += ws / Wsum;   // entropy_element
    if (last) {
      for (int j = 0; j < KB_; ++j) {
        dout[13376 + i * 8 + j] = res[1 + j] - logI;     // log_R_s
        dout[17984 + i * 8 + j] = phi[j];                // phi_k
        for (int l = 0; l < KB_; ++l) {
          float v = (l == j) ? 0.f : (res[r6_pidx(j, l)] - res[1 + j]);
          dout[13888 + i * 64 + j * 8 + l] = v;          // log_R_ss
        }
      }
    }
  }
}

// final: walk ancestor chains to rebuild histories, pack all outputs (float32)
__global__ __launch_bounds__(512) void r6_final(const float* lv_arr, const int* s_arr,
                                                const int* o_arr, const float* accum,
                                                float* dout) {
  int r = threadIdx.x;   // one thread per final beam row (beam-major j*64+i)
  int i = r & 63, j = r >> 6;
  float vals[LL]; int svs[LL];
  int a = r;
  for (int tt = LL - 1; tt >= 0; --tt) {
    vals[tt] = lv_arr[tt * RR + a];
    svs[tt]  = s_arr[tt * RR + a];
    a = o_arr[tt * RR + a];
  }
  #pragma unroll
  for (int tt = 0; tt < LL; ++tt) {
    dout[i * 104 + j * 13 + tt] = vals[tt];               // outputs
    dout[6656 + i * 104 + j * 13 + tt] = (float)svs[tt];  // samples
  }
  if (r < 64) {
    dout[13312 + r] = accum[64 + r];   // entropy_element
    dout[18496 + r] = accum[r];        // ent_plot
  }
}

extern "C" void kernel_launch(void* const* d_in, const int* in_sizes, int n_in,
                              void* d_out, int out_size, void* d_ws, size_t ws_size,
                              hipStream_t stream) {
  const float* x_feat  = (const float*)d_in[0];
  const float* W_in_op = (const float*)d_in[1];
  const float* b_in_op = (const float*)d_in[2];
  const float* W_ih    = (const float*)d_in[3];
  const float* W_hh    = (const float*)d_in[4];
  const float* b_ih    = (const float*)d_in[5];
  const float* b_hh    = (const float*)d_in[6];
  const float* W_fc1   = (const float*)d_in[7];
  const float* b_fc1   = (const float*)d_in[8];
  const float* W_out   = (const float*)d_in[9];
  const float* b_out   = (const float*)d_in[10];
  const float* gum     = (const float*)d_in[11];
  float* out           = (float*)d_out;     // float32 output (round-4 finding)

  float* W = (float*)d_ws;
  size_t o = 0;
  float* lv_arr = W + o; o += (size_t)LL * RR;
  float* Gv     = W + o; o += RR;
  float* logpb0 = W + o; o += RR;
  float* logpb1 = W + o; o += RR;
  float* entold = W + o; o += RR;
  float* entbm  = W + o; o += RR;
  float* accum  = W + o; o += 128;
  int* s_arr = (int*)(W + o); o += (size_t)LL * RR;
  int* o_arr = (int*)(W + o); o += (size_t)LL * RR;
  float* xfb    = W + o; o += (size_t)64 * GD;
  float* inp    = W + o; o += (size_t)RR * 128;
  float* logits = W + o; o += (size_t)RR * VV;
  float* lp     = W + o; o += (size_t)RR * VV;
  float* gb     = W + o; o += (size_t)RR * VV;
  float* hb     = W + o; o += (size_t)RR * HD_;
  float* cb     = W + o; o += (size_t)RR * HD_;
  float* htmp   = W + o; o += (size_t)RR * HD_;
  float* ctmp   = W + o; o += (size_t)RR * HD_;
  float* hd     = W + o; o += (size_t)RR * HD_;
  size_t needed_bytes = o * sizeof(float);
  float* logpb[2] = {logpb0, logpb1};

  if (ws_size < needed_bytes) {
    r6_flag<<<(OUT_N + 255) / 256, 256, 0, stream>>>(out);
    return;
  }

  r6_wszero<<<2048, 256, 0, stream>>>(hb, cb, Gv, logpb[0], accum);
  r6_xfb<<<64, 256, 0, stream>>>(x_feat, W_ih, b_ih, b_hh, xfb);

  for (int t = 0; t < LL; ++t) {
    int pi = t & 1, po = pi ^ 1;
    r6_inp<<<256, 256, 0, stream>>>(s_arr, t, W_in_op, b_in_op, inp);
    r6_glstm<<<dim3(16, 8), 256, 0, stream>>>(hb, inp, W_hh, W_ih, xfb, cb, ctmp, htmp);
    r6_fc1<<<dim3(16, 8), 256, 0, stream>>>(htmp, W_fc1, b_fc1, hd);
    r6_out<<<dim3(7, 8), 256, 0, stream>>>(hd, W_out, b_out, logits);
    r6_soft<<<512, 256, 0, stream>>>(logits, logpb[pi], Gv,
                                     gum + (size_t)t * RR * VV, lp, gb, entold);
    r6_topk<<<64, 256, 0, stream>>>(gb, t, Gv, s_arr + (size_t)t * RR,
                                    o_arr + (size_t)t * RR);
    r6_rb<<<2048, 256, 0, stream>>>(htmp, ctmp, o_arr + (size_t)t * RR, hb, cb);
    r6_sel<<<1, 512, 0, stream>>>(lp, o_arr + (size_t)t * RR, s_arr + (size_t)t * RR,
                                  logpb[pi], logpb[po], entold, entbm,
                                  lv_arr + (size_t)t * RR);
    r6_logR<<<64, 256, 0, stream>>>(logpb[po], entbm, accum, out, (t == LL - 1) ? 1 : 0);
  }
  r6_final<<<1, 512, 0, stream>>>(lv_arr, s_arr, o_arr, accum, out);
}

// Round 7
// 2993.768 us; speedup vs baseline: 7.9316x; 1.7350x over previous
//
#include <hip/hip_runtime.h>
#include <hip/hip_bf16.h>
#include <cstdint>

#define RR 512          // B*K rows
#define KB_ 8           // beams
#define VV 400          // vocab
#define HD_ 1024
#define GD 4096         // 4*HD
#define LL 13           // program_len
#define BKT 16          // GEMM K-tile
#define NPTS 1000       // integration points
#define OUT_N 18560
#define LDP 68          // padded LDS leading dim (68 mod 32 = 4 -> 2-way max)

// unordered pair tables (j<l) for the 28 off-diagonal logsumexp reductions
__device__ __constant__ int cPJ[28] = {0,0,0,0,0,0,0,1,1,1,1,1,1,2,2,2,2,2,3,3,3,3,4,4,4,5,5,6};
__device__ __constant__ int cPL[28] = {1,2,3,4,5,6,7,2,3,4,5,6,7,3,4,5,6,7,4,5,6,7,5,6,7,6,7,7};

__device__ __forceinline__ float r7_log1mexp(float x) {
  x = fminf(x, -1e-38f);
  return (x > -0.6931472f) ? logf(-expm1f(x)) : log1pf(-expf(x));
}

__device__ __forceinline__ float r7_sigm(float x) { return 1.f / (1.f + expf(-x)); }

__device__ __forceinline__ int r7_pidx(int j, int l) {
  if (j > l) { int t = j; j = l; l = t; }
  return 9 + (j * (15 - j)) / 2 + (l - j - 1);
}

// ---- block (256 threads = 4 waves) reductions (used by soft) ----
__device__ __forceinline__ float r7_bmax256(float v, float* red) {
  #pragma unroll
  for (int o = 32; o; o >>= 1) v = fmaxf(v, __shfl_xor(v, o, 64));
  __syncthreads();
  if ((threadIdx.x & 63) == 0) red[threadIdx.x >> 6] = v;
  __syncthreads();
  return fmaxf(fmaxf(red[0], red[1]), fmaxf(red[2], red[3]));
}

__device__ __forceinline__ float r7_bsum256(float v, float* red) {
  #pragma unroll
  for (int o = 32; o; o >>= 1) v += __shfl_xor(v, o, 64);
  __syncthreads();
  if ((threadIdx.x & 63) == 0) red[threadIdx.x >> 6] = v;
  __syncthreads();
  return (red[0] + red[1]) + (red[2] + red[3]);
}

// ---- fp32 tiled GEMM core (padded LDS): C(64x64) += A[r0..,:K] * W[n0..,:K]^T ----
__device__ __forceinline__ void r7_gemm(
    const float* __restrict__ A, int lda,
    const float* __restrict__ W, int ldw,
    int K, int r0, int n0, int nmax,
    float (&acc)[4][4], float (*As)[LDP], float (*Bs)[LDP])
{
  const int tid = threadIdx.x;
  const int la = tid >> 2;          // 0..63
  const int lk = (tid & 3) << 2;    // 0,4,8,12
  const int tx = tid & 15, ty = tid >> 4;
  for (int k0 = 0; k0 < K; k0 += BKT) {
    float4 av = *reinterpret_cast<const float4*>(A + (size_t)(r0 + la) * lda + (k0 + lk));
    float4 bv = make_float4(0.f, 0.f, 0.f, 0.f);
    if (n0 + la < nmax)
      bv = *reinterpret_cast<const float4*>(W + (size_t)(n0 + la) * ldw + (k0 + lk));
    __syncthreads();
    As[lk + 0][la] = av.x; As[lk + 1][la] = av.y; As[lk + 2][la] = av.z; As[lk + 3][la] = av.w;
    Bs[lk + 0][la] = bv.x; Bs[lk + 1][la] = bv.y; Bs[lk + 2][la] = bv.z; Bs[lk + 3][la] = bv.w;
    __syncthreads();
    #pragma unroll
    for (int kk = 0; kk < BKT; ++kk) {
      float4 a = *reinterpret_cast<const float4*>(&As[kk][ty * 4]);
      float4 b = *reinterpret_cast<const float4*>(&Bs[kk][tx * 4]);
      float ar[4] = {a.x, a.y, a.z, a.w};
      float br[4] = {b.x, b.y, b.z, b.w};
      #pragma unroll
      for (int i = 0; i < 4; ++i)
        #pragma unroll
        for (int j = 0; j < 4; ++j)
          acc[i][j] = fmaf(ar[i], br[j], acc[i][j]);
    }
  }
}

// ---- zero the carried-state workspace pieces ----
__global__ __launch_bounds__(256) void r7_wszero(float* h0, float* c0, float* Gv,
                                                 float* logp0, float* accum) {
  int idx = blockIdx.x * 256 + threadIdx.x;
  if (idx < RR * HD_) { h0[idx] = 0.f; c0[idx] = 0.f; }
  if (idx < RR) { Gv[idx] = 0.f; logp0[idx] = 0.f; }
  if (idx < 128) accum[idx] = 0.f;
}

__global__ __launch_bounds__(256) void r7_flag(float* dout) {
  int idx = blockIdx.x * 256 + threadIdx.x;
  if (idx < OUT_N) dout[idx] = (idx == 6656) ? 20000.0f : 0.0f;
}

// xfb once
__global__ __launch_bounds__(256) void r7_xfb(const float* __restrict__ xf,
                                              const float* __restrict__ Wih,
                                              const float* __restrict__ bih,
                                              const float* __restrict__ bhh,
                                              float* __restrict__ xfb) {
  __shared__ __align__(16) float As[BKT][LDP];
  __shared__ __align__(16) float Bs[BKT][LDP];
  float acc[4][4] = {};
  int n0 = blockIdx.x * 64;
  r7_gemm(xf, 1024, Wih, 1152, 1024, 0, n0, 1 << 30, acc, As, Bs);
  int tx = threadIdx.x & 15, ty = threadIdx.x >> 4;
  #pragma unroll
  for (int i = 0; i < 4; ++i)
    #pragma unroll
    for (int j = 0; j < 4; ++j) {
      int r = ty * 4 + i, c = n0 + tx * 4 + j;
      xfb[(size_t)r * GD + c] = acc[i][j] + bih[c] + bhh[c];
    }
}

// inp_op[r,m] = relu(W_in_op[m, s] + b_in_op[m])
__global__ __launch_bounds__(256) void r7_inp(const int* s_arr, int t, const float* Wio,
                                              const float* bio, float* inp) {
  int idx = blockIdx.x * 256 + threadIdx.x;   // 512*128
  int r = idx >> 7, m = idx & 127;
  int s = (t == 0) ? 400 : s_arr[(size_t)(t - 1) * RR + r];
  float v = Wio[m * 401 + s] + bio[m];
  inp[idx] = fmaxf(v, 0.f);
}

// gates GEMM: gate-pair per blockIdx.z, A rows gathered via parent order.
// grid (16, 8, 2), 256 threads; tile 64r x 64c x 2 gates.
__global__ __launch_bounds__(256) void r7_glstm(
    const float* __restrict__ hprev, const float* __restrict__ inp,
    const float* __restrict__ Whh, const float* __restrict__ Wih,
    const int* __restrict__ o_arr, int t, float* __restrict__ gates)
{
  __shared__ __align__(16) float As[BKT][LDP];
  __shared__ __align__(16) float Bs2[2][BKT][LDP];
  float acc[2][4][4] = {};
  const int tid = threadIdx.x;
  const int n0 = blockIdx.x * 64, r0 = blockIdx.y * 64, g2 = blockIdx.z;
  const int la = tid >> 2, lk = (tid & 3) << 2;
  const int gl = tid >> 7, rem = tid & 127;
  const int lb = rem >> 1, lk2 = (rem & 1) * 8;
  const int tx = tid & 15, ty = tid >> 4;
  const int arow = r0 + la;
  const int asrc = (t == 0) ? arow : o_arr[(size_t)(t - 1) * RR + arow];
  const float* Arow = hprev + (size_t)asrc * HD_;
  const float* Brow = Whh + (size_t)((2 * g2 + gl) * 1024 + n0 + lb) * HD_;
  for (int k0 = 0; k0 < HD_; k0 += BKT) {
    float4 av = *reinterpret_cast<const float4*>(Arow + k0 + lk);
    float4 b0 = *reinterpret_cast<const float4*>(Brow + k0 + lk2);
    float4 b1 = *reinterpret_cast<const float4*>(Brow + k0 + lk2 + 4);
    __syncthreads();
    As[lk + 0][la] = av.x; As[lk + 1][la] = av.y; As[lk + 2][la] = av.z; As[lk + 3][la] = av.w;
    Bs2[gl][lk2 + 0][lb] = b0.x; Bs2[gl][lk2 + 1][lb] = b0.y;
    Bs2[gl][lk2 + 2][lb] = b0.z; Bs2[gl][lk2 + 3][lb] = b0.w;
    Bs2[gl][lk2 + 4][lb] = b1.x; Bs2[gl][lk2 + 5][lb] = b1.y;
    Bs2[gl][lk2 + 6][lb] = b1.z; Bs2[gl][lk2 + 7][lb] = b1.w;
    __syncthreads();
    #pragma unroll
    for (int kk = 0; kk < BKT; ++kk) {
      float4 a = *reinterpret_cast<const float4*>(&As[kk][ty * 4]);
      float4 bA = *reinterpret_cast<const float4*>(&Bs2[0][kk][tx * 4]);
      float4 bB = *reinterpret_cast<const float4*>(&Bs2[1][kk][tx * 4]);
      float ar[4] = {a.x, a.y, a.z, a.w};
      float b0r[4] = {bA.x, bA.y, bA.z, bA.w};
      float b1r[4] = {bB.x, bB.y, bB.z, bB.w};
      #pragma unroll
      for (int i = 0; i < 4; ++i)
        #pragma unroll
        for (int j = 0; j < 4; ++j) {
          acc[0][i][j] = fmaf(ar[i], b0r[j], acc[0][i][j]);
          acc[1][i][j] = fmaf(ar[i], b1r[j], acc[1][i][j]);
        }
    }
  }
  // inp @ W_ih[:,1024:1152]^T  (K=128, rows NOT gathered)
  const float* A2 = inp + (size_t)(r0 + la) * 128;
  const float* B2 = Wih + (size_t)((2 * g2 + gl) * 1024 + n0 + lb) * 1152 + 1024;
  for (int k0 = 0; k0 < 128; k0 += BKT) {
    float4 av = *reinterpret_cast<const float4*>(A2 + k0 + lk);
    float4 b0 = *reinterpret_cast<const float4*>(B2 + k0 + lk2);
    float4 b1 = *reinterpret_cast<const float4*>(B2 + k0 + lk2 + 4);
    __syncthreads();
    As[lk + 0][la] = av.x; As[lk + 1][la] = av.y; As[lk + 2][la] = av.z; As[lk + 3][la] = av.w;
    Bs2[gl][lk2 + 0][lb] = b0.x; Bs2[gl][lk2 + 1][lb] = b0.y;
    Bs2[gl][lk2 + 2][lb] = b0.z; Bs2[gl][lk2 + 3][lb] = b0.w;
    Bs2[gl][lk2 + 4][lb] = b1.x; Bs2[gl][lk2 + 5][lb] = b1.y;
    Bs2[gl][lk2 + 6][lb] = b1.z; Bs2[gl][lk2 + 7][lb] = b1.w;
    __syncthreads();
    #pragma unroll
    for (int kk = 0; kk < BKT; ++kk) {
      float4 a = *reinterpret_cast<const float4*>(&As[kk][ty * 4]);
      float4 bA = *reinterpret_cast<const float4*>(&Bs2[0][kk][tx * 4]);
      float4 bB = *reinterpret_cast<const float4*>(&Bs2[1][kk][tx * 4]);
      float ar[4] = {a.x, a.y, a.z, a.w};
      float b0r[4] = {bA.x, bA.y, bA.z, bA.w};
      float b1r[4] = {bB.x, bB.y, bB.z, bB.w};
      #pragma unroll
      for (int i = 0; i < 4; ++i)
        #pragma unroll
        for (int j = 0; j < 4; ++j) {
          acc[0][i][j] = fmaf(ar[i], b0r[j], acc[0][i][j]);
          acc[1][i][j] = fmaf(ar[i], b1r[j], acc[1][i][j]);
        }
    }
  }
  #pragma unroll
  for (int g = 0; g < 2; ++g)
    #pragma unroll
    for (int i = 0; i < 4; ++i)
      #pragma unroll
      for (int j = 0; j < 4; ++j)
        gates[(size_t)(r0 + ty * 4 + i) * GD + (2 * g2 + g) * 1024 + n0 + tx * 4 + j] =
            acc[g][i][j];
}

// LSTM pointwise: + xfb, gathered c_prev
__global__ __launch_bounds__(256) void r7_lstm(const float* gates, const float* xfb,
                                               const float* cprev, const int* o_arr, int t,
                                               float* cout, float* hout) {
  int idx = blockIdx.x * 256 + threadIdx.x;   // 512*1024
  int r = idx >> 10, n = idx & 1023;
  int src = (t == 0) ? r : o_arr[(size_t)(t - 1) * RR + r];
  const float* g = gates + (size_t)r * GD;
  const float* xb = xfb + (size_t)(r & 63) * GD;
  float gi = g[n] + xb[n];
  float gf = g[1024 + n] + xb[1024 + n];
  float gg = g[2048 + n] + xb[2048 + n];
  float go = g[3072 + n] + xb[3072 + n];
  float cp = cprev[(size_t)src * HD_ + n];
  float c = r7_sigm(gf) * cp + r7_sigm(gi) * tanhf(gg);
  cout[idx] = c;
  hout[idx] = r7_sigm(go) * tanhf(c);
}

// fc1 K-split: grid (16,8,2); partial (no bias/relu) -> hdp[z]
__global__ __launch_bounds__(256) void r7_fc1(const float* h, const float* W1, float* hdp) {
  __shared__ __align__(16) float As[BKT][LDP];
  __shared__ __align__(16) float Bs[BKT][LDP];
  float acc[4][4] = {};
  int n0 = blockIdx.x * 64, r0 = blockIdx.y * 64, z = blockIdx.z;
  r7_gemm(h + z * 512, HD_, W1 + z * 512, HD_, 512, r0, n0, 1 << 30, acc, As, Bs);
  float* dst = hdp + (size_t)z * RR * HD_;
  int tx = threadIdx.x & 15, ty = threadIdx.x >> 4;
  #pragma unroll
  for (int i = 0; i < 4; ++i)
    #pragma unroll
    for (int j = 0; j < 4; ++j)
      dst[(size_t)(r0 + ty * 4 + i) * HD_ + n0 + tx * 4 + j] = acc[i][j];
}

// combine fc1 partials + bias + relu
__global__ __launch_bounds__(256) void r7_fc1c(const float* hdp, const float* b1, float* hd) {
  int idx = blockIdx.x * 256 + threadIdx.x;   // 524288
  hd[idx] = fmaxf(hdp[idx] + hdp[RR * HD_ + idx] + b1[idx & 1023], 0.f);
}

// out K-split: grid (7,8,4); partial -> outp[z]
__global__ __launch_bounds__(256) void r7_out(const float* hd, const float* Wo, float* outp) {
  __shared__ __align__(16) float As[BKT][LDP];
  __shared__ __align__(16) float Bs[BKT][LDP];
  float acc[4][4] = {};
  int n0 = blockIdx.x * 64, r0 = blockIdx.y * 64, z = blockIdx.z;
  r7_gemm(hd + z * 256, HD_, Wo + z * 256, HD_, 256, r0, n0, VV, acc, As, Bs);
  float* dst = outp + (size_t)z * RR * VV;
  int tx = threadIdx.x & 15, ty = threadIdx.x >> 4;
  #pragma unroll
  for (int i = 0; i < 4; ++i)
    #pragma unroll
    for (int j = 0; j < 4; ++j) {
      int c = n0 + tx * 4 + j;
      if (c < VV) dst[(size_t)(r0 + ty * 4 + i) * VV + c] = acc[i][j];
    }
}

// per-row: combine logit partials + bias, log_softmax, entropy, gumbel-with-max
__global__ __launch_bounds__(256) void r7_soft(const float* outp, const float* bo,
                                               const float* logp_in, const float* Gv,
                                               const float* gum, float* lp, float* gb,
                                               float* entold) {
  __shared__ float red[4];
  int r = blockIdx.x, tid = threadIdx.x;
  bool v1 = (tid + 256) < VV;
  size_t off0 = (size_t)r * VV + tid;
  float l0 = outp[off0] + outp[RR * VV + off0] + outp[2 * RR * VV + off0]
           + outp[3 * RR * VV + off0] + bo[tid];
  float l1 = -INFINITY;
  if (v1) {
    size_t off1 = off0 + 256;
    l1 = outp[off1] + outp[RR * VV + off1] + outp[2 * RR * VV + off1]
       + outp[3 * RR * VV + off1] + bo[tid + 256];
  }
  float m = r7_bmax256(fmaxf(l0, l1), red);
  float e0 = expf(l0 - m), e1 = v1 ? expf(l1 - m) : 0.f;
  float s = r7_bsum256(e0 + e1, red);
  float ls = logf(s);
  float lp0 = l0 - m - ls, lp1 = l1 - m - ls;
  float ent = lp0 * expf(lp0) + (v1 ? lp1 * expf(lp1) : 0.f);
  ent = r7_bsum256(ent, red);
  if (tid == 0) entold[r] = ent;
  float lpr = logp_in[r];
  const float* ur = gum + (size_t)r * VV;
  float gp0, gp1 = -INFINITY;
  { float u = ur[tid];
    gp0 = lp0 + lpr - logf(-logf(u * (1.f - 2e-7f) + 1e-7f)); }
  if (v1) { float u = ur[tid + 256];
            gp1 = lp1 + lpr - logf(-logf(u * (1.f - 2e-7f) + 1e-7f)); }
  float Z = r7_bmax256(fmaxf(gp0, gp1), red);
  float T = Gv[r];
  int i = r & 63, j = r >> 6;
  float* gbr = gb + (size_t)i * (KB_ * VV) + j * VV;
  {
    float vv = T - gp0 + r7_log1mexp(gp0 - Z);
    gbr[tid] = T - fmaxf(vv, 0.f) - log1pf(expf(-fabsf(vv)));
    lp[(size_t)r * VV + tid] = lp0;
  }
  if (v1) {
    float vv = T - gp1 + r7_log1mexp(gp1 - Z);
    gbr[tid + 256] = T - fmaxf(vv, 0.f) - log1pf(expf(-fabsf(vv)));
    lp[(size_t)r * VV + tid + 256] = lp1;
  }
}

// pack (value, index) so u64-max == (max value, tie -> lower index)
__device__ __forceinline__ unsigned long long r7_pack(float v, int c) {
  unsigned u = __float_as_uint(v);
  u = (u & 0x80000000u) ? ~u : (u | 0x80000000u);
  return ((unsigned long long)u << 32) | (unsigned)(0xFFFFFFFFu - (unsigned)c);
}

// per-batch top-8 via register-cached candidates + wave reduce; sel folded in.
__global__ __launch_bounds__(256) void r7_topk(const float* gb, int t, float* Gv,
                                               int* s_t, int* o_t, const float* lp,
                                               const float* logp_in, float* logp_out,
                                               const float* entold, float* entbm,
                                               float* lv_t) {
  __shared__ unsigned long long wbest[4];
  __shared__ unsigned long long selK[KB_];
  int i = blockIdx.x, tid = threadIdx.x;
  int lane = tid & 63, wid = tid >> 6;
  int limit = (t == 0) ? VV : KB_ * VV;
  unsigned long long key[13];
  int cnt = 0;
  for (int c = tid; c < limit; c += 256)
    key[cnt++] = r7_pack(gb[(size_t)i * (KB_ * VV) + c], c);
  for (int it = 0; it < KB_; ++it) {
    unsigned long long b = 0ull;
    for (int k = 0; k < cnt; ++k) b = (key[k] > b) ? key[k] : b;
    #pragma unroll
    for (int o = 32; o; o >>= 1) {
      unsigned long long x = __shfl_xor(b, o, 64);
      b = (x > b) ? x : b;
    }
    if (lane == 0) wbest[wid] = b;
    __syncthreads();
    unsigned long long g = wbest[0];
    g = (wbest[1] > g) ? wbest[1] : g;
    g = (wbest[2] > g) ? wbest[2] : g;
    g = (wbest[3] > g) ? wbest[3] : g;
    int csel = (int)(0xFFFFFFFFu - (unsigned)(g & 0xFFFFFFFFu));
    if (tid == (csel & 255)) key[csel >> 8] = 0ull;   // clear winner
    if (tid == 0) selK[it] = g;
    __syncthreads();
  }
  if (tid < KB_) {
    unsigned long long g = selK[tid];
    unsigned x = (unsigned)(g >> 32);
    x = (x & 0x80000000u) ? (x & 0x7FFFFFFFu) : ~x;
    float v = __uint_as_float(x);
    int c = (int)(0xFFFFFFFFu - (unsigned)(g & 0xFFFFFFFFu));
    int r = tid * 64 + i;
    int s = c % VV;
    int o = (c / VV) * 64 + i;
    Gv[r] = v;
    s_t[r] = s;
    o_t[r] = o;
    float lv = lp[(size_t)o * VV + s];
    logp_out[r] = logp_in[o] + lv;
    entbm[r] = entold[o];
    lv_t[r] = lv;
  }
}

// compute_log_R per batch: 37 logsumexps distributed over 4 waves (shuffle-only)
__global__ __launch_bounds__(256) void r7_logR(const float* logp_new, const float* entbm,
                                               float* accum, float* dout, int last) {
  __shared__ float Tm[KB_][NPTS];
  __shared__ float base[NPTS];
  __shared__ float phi[KB_], pj[KB_];
  __shared__ float res[37];
  int i = blockIdx.x, tid = threadIdx.x;
  int lane = tid & 63, wid = tid >> 6;
  if (tid < KB_) { float ph = logp_new[tid * 64 + i]; phi[tid] = ph; pj[tid] = expf(ph); }
  __syncthreads();
  float pS = ((pj[0] + pj[1]) + (pj[2] + pj[3])) + ((pj[4] + pj[5]) + (pj[6] + pj[7]));
  for (int n = tid; n < NPTS; n += 256) {
    float lu = logf((n + 0.5f) * (1.0f / NPTS));
    float b = -pS * lu;
    #pragma unroll
    for (int j = 0; j < KB_; ++j) {
      float tv = r7_log1mexp(pj[j] * lu);
      Tm[j][n] = tv; b += tv;
    }
    base[n] = b;
  }
  __syncthreads();
  const float logN = 6.9077552789821f;   // log(1000)
  for (int ridx = wid; ridx < 37; ridx += 4) {
    int jj = -1, ll = -1;
    if (ridx >= 1 && ridx < 9) jj = ridx - 1;
    else if (ridx >= 9) { jj = cPJ[ridx - 9]; ll = cPL[ridx - 9]; }
    float mx = -INFINITY;
    for (int n = lane; n < NPTS; n += 64) {
      float v = base[n];
      if (jj >= 0) v -= Tm[jj][n];
      if (ll >= 0) v -= Tm[ll][n];
      mx = fmaxf(mx, v);
    }
    #pragma unroll
    for (int o = 32; o; o >>= 1) mx = fmaxf(mx, __shfl_xor(mx, o, 64));
    float sm = 0.f;
    for (int n = lane; n < NPTS; n += 64) {
      float v = base[n];
      if (jj >= 0) v -= Tm[jj][n];
      if (ll >= 0) v -= Tm[ll][n];
      sm += expf(v - mx);
    }
    #pragma unroll
    for (int o = 32; o; o >>= 1) sm += __shfl_xor(sm, o, 64);
    if (lane == 0) res[ridx] = mx + logf(sm) - logN;
  }
  __syncthreads();
  if (tid == 0) {
    float logI = res[0];
    float Wsum = 0.f, ws = 0.f;
    #pragma unroll
    for (int j = 0; j < KB_; ++j) {
      float lRs = res[1 + j] - logI;
      float wj = expf(phi[j] + lRs);
      Wsum += wj;
      ws += wj * entbm[j * 64 + i];
    }
    accum[i] += ws;               // ent_plot
    accum[64 + i] += ws / Wsum;   // entropy_element
    if (last) {
      for (int j = 0; j < KB_; ++j) {
        dout[13376 + i * 8 + j] = res[1 + j] - logI;     // log_R_s
        dout[17984 + i * 8 + j] = phi[j];                // phi_k
        for (int l = 0; l < KB_; ++l) {
          float v = (l == j) ? 0.f : (res[r7_pidx(j, l)] - res[1 + j]);
          dout[13888 + i * 64 + j * 8 + l] = v;          // log_R_ss
        }
      }
    }
  }
}

// final: walk ancestor chains, pack all outputs (float32)
__global__ __launch_bounds__(512) void r7_final(const float* lv_arr, const int* s_arr,
                                                const int* o_arr, const float* accum,
                                                float* dout) {
  int r = threadIdx.x;
  int i = r & 63, j = r >> 6;
  float vals[LL]; int svs[LL];
  int a = r;
  for (int tt = LL - 1; tt >= 0; --tt) {
    vals[tt] = lv_arr[tt * RR + a];
    svs[tt]  = s_arr[tt * RR + a];
    a = o_arr[tt * RR + a];
  }
  #pragma unroll
  for (int tt = 0; tt < LL; ++tt) {
    dout[i * 104 + j * 13 + tt] = vals[tt];
    dout[6656 + i * 104 + j * 13 + tt] = (float)svs[tt];
  }
  if (r < 64) {
    dout[13312 + r] = accum[64 + r];   // entropy_element
    dout[18496 + r] = accum[r];        // ent_plot
  }
}

extern "C" void kernel_launch(void* const* d_in, const int* in_sizes, int n_in,
                              void* d_out, int out_size, void* d_ws, size_t ws_size,
                              hipStream_t stream) {
  const float* x_feat  = (const float*)d_in[0];
  const float* W_in_op = (const float*)d_in[1];
  const float* b_in_op = (const float*)d_in[2];
  const float* W_ih    = (const float*)d_in[3];
  const float* W_hh    = (const float*)d_in[4];
  const float* b_ih    = (const float*)d_in[5];
  const float* b_hh    = (const float*)d_in[6];
  const float* W_fc1   = (const float*)d_in[7];
  const float* b_fc1   = (const float*)d_in[8];
  const float* W_out   = (const float*)d_in[9];
  const float* b_out   = (const float*)d_in[10];
  const float* gum     = (const float*)d_in[11];
  float* out           = (float*)d_out;

  float* W = (float*)d_ws;
  size_t o = 0;
  float* lv_arr = W + o; o += (size_t)LL * RR;
  float* Gv     = W + o; o += RR;
  float* logpb0 = W + o; o += RR;
  float* logpb1 = W + o; o += RR;
  float* entold = W + o; o += RR;
  float* entbm  = W + o; o += RR;
  float* accum  = W + o; o += 128;
  int* s_arr = (int*)(W + o); o += (size_t)LL * RR;
  int* o_arr = (int*)(W + o); o += (size_t)LL * RR;
  float* xfb    = W + o; o += (size_t)64 * GD;
  float* inp    = W + o; o += (size_t)RR * 128;
  float* gates  = W + o; o += (size_t)RR * GD;        // aliased: hdp[2] then outp[4]
  float* lp     = W + o; o += (size_t)RR * VV;
  float* gb     = W + o; o += (size_t)RR * VV;
  float* h2[2]; h2[0] = W + o; o += (size_t)RR * HD_; h2[1] = W + o; o += (size_t)RR * HD_;
  float* c2[2]; c2[0] = W + o; o += (size_t)RR * HD_; c2[1] = W + o; o += (size_t)RR * HD_;
  float* hd     = W + o; o += (size_t)RR * HD_;
  size_t needed_bytes = o * sizeof(float);
  float* logpb[2] = {logpb0, logpb1};
  float* hdp  = gates;            // 2 x RR*HD_  (fc1 partials)
  float* outp = gates;            // 4 x RR*VV   (out partials, after hdp dead)

  if (ws_size < needed_bytes) {
    r7_flag<<<(OUT_N + 255) / 256, 256, 0, stream>>>(out);
    return;
  }

  r7_wszero<<<2048, 256, 0, stream>>>(h2[0], c2[0], Gv, logpb[0], accum);
  r7_xfb<<<64, 256, 0, stream>>>(x_feat, W_ih, b_ih, b_hh, xfb);

  for (int t = 0; t < LL; ++t) {
    int pi = t & 1, po = pi ^ 1;
    r7_inp<<<256, 256, 0, stream>>>(s_arr, t, W_in_op, b_in_op, inp);
    r7_glstm<<<dim3(16, 8, 2), 256, 0, stream>>>(h2[pi], inp, W_hh, W_ih, o_arr, t, gates);
    r7_lstm<<<2048, 256, 0, stream>>>(gates, xfb, c2[pi], o_arr, t, c2[po], h2[po]);
    r7_fc1<<<dim3(16, 8, 2), 256, 0, stream>>>(h2[po], W_fc1, hdp);
    r7_fc1c<<<2048, 256, 0, stream>>>(hdp, b_fc1, hd);
    r7_out<<<dim3(7, 8, 4), 256, 0, stream>>>(hd, W_out, outp);
    r7_soft<<<512, 256, 0, stream>>>(outp, b_out, logpb[pi], Gv,
                                     gum + (size_t)t * RR * VV, lp, gb, entold);
    r7_topk<<<64, 256, 0, stream>>>(gb, t, Gv, s_arr + (size_t)t * RR,
                                    o_arr + (size_t)t * RR, lp, logpb[pi], logpb[po],
                                    entold, entbm, lv_arr + (size_t)t * RR);
    r7_logR<<<64, 256, 0, stream>>>(logpb[po], entbm, accum, out, (t == LL - 1) ? 1 : 0);
  }
  r7_final<<<1, 512, 0, stream>>>(lv_arr, s_arr, o_arr, accum, out);
}

// Round 9
// 2758.354 us; speedup vs baseline: 8.6085x; 1.0853x over previous
//
#include <hip/hip_runtime.h>
#include <hip/hip_bf16.h>
#include <cstdint>

#define RR 512          // B*K rows
#define KB_ 8           // beams
#define VV 400          // vocab
#define HD_ 1024
#define GD 4096         // 4*HD
#define LL 13           // program_len
#define BKT 16          // GEMM K-tile
#define NPTS 1000       // integration points
#define OUT_N 18560
#define LDP 68          // padded LDS leading dim for 64-wide tiles
#define AP 36           // padded leading dim, 32-row A tile
#define BP 132          // padded leading dim, 128-col B tile

// unordered pair tables (j<l) for the 28 off-diagonal logsumexp reductions
__device__ __constant__ int cPJ[28] = {0,0,0,0,0,0,0,1,1,1,1,1,1,2,2,2,2,2,3,3,3,3,4,4,4,5,5,6};
__device__ __constant__ int cPL[28] = {1,2,3,4,5,6,7,2,3,4,5,6,7,3,4,5,6,7,4,5,6,7,5,6,7,6,7,7};

__device__ __forceinline__ float r9_log1mexp(float x) {
  x = fminf(x, -1e-38f);
  return (x > -0.6931472f) ? logf(-expm1f(x)) : log1pf(-expf(x));
}

__device__ __forceinline__ float r9_sigm(float x) { return 1.f / (1.f + expf(-x)); }

__device__ __forceinline__ int r9_pidx(int j, int l) {
  if (j > l) { int t = j; j = l; l = t; }
  return 9 + (j * (15 - j)) / 2 + (l - j - 1);
}

// ---- block (256 threads = 4 waves) reductions ----
__device__ __forceinline__ float r9_bmax256(float v, float* red) {
  #pragma unroll
  for (int o = 32; o; o >>= 1) v = fmaxf(v, __shfl_xor(v, o, 64));
  __syncthreads();
  if ((threadIdx.x & 63) == 0) red[threadIdx.x >> 6] = v;
  __syncthreads();
  return fmaxf(fmaxf(red[0], red[1]), fmaxf(red[2], red[3]));
}

__device__ __forceinline__ float r9_bsum256(float v, float* red) {
  #pragma unroll
  for (int o = 32; o; o >>= 1) v += __shfl_xor(v, o, 64);
  __syncthreads();
  if ((threadIdx.x & 63) == 0) red[threadIdx.x >> 6] = v;
  __syncthreads();
  return (red[0] + red[1]) + (red[2] + red[3]);
}

// ---- fp32 tiled GEMM core (64x64, padded LDS) ----
__device__ __forceinline__ void r9_gemm(
    const float* __restrict__ A, int lda,
    const float* __restrict__ W, int ldw,
    int K, int r0, int n0, int nmax,
    float (&acc)[4][4], float (*As)[LDP], float (*Bs)[LDP])
{
  const int tid = threadIdx.x;
  const int la = tid >> 2;          // 0..63
  const int lk = (tid & 3) << 2;    // 0,4,8,12
  const int tx = tid & 15, ty = tid >> 4;
  for (int k0 = 0; k0 < K; k0 += BKT) {
    float4 av = *reinterpret_cast<const float4*>(A + (size_t)(r0 + la) * lda + (k0 + lk));
    float4 bv = make_float4(0.f, 0.f, 0.f, 0.f);
    if (n0 + la < nmax)
      bv = *reinterpret_cast<const float4*>(W + (size_t)(n0 + la) * ldw + (k0 + lk));
    __syncthreads();
    As[lk + 0][la] = av.x; As[lk + 1][la] = av.y; As[lk + 2][la] = av.z; As[lk + 3][la] = av.w;
    Bs[lk + 0][la] = bv.x; Bs[lk + 1][la] = bv.y; Bs[lk + 2][la] = bv.z; Bs[lk + 3][la] = bv.w;
    __syncthreads();
    #pragma unroll
    for (int kk = 0; kk < BKT; ++kk) {
      float4 a = *reinterpret_cast<const float4*>(&As[kk][ty * 4]);
      float4 b = *reinterpret_cast<const float4*>(&Bs[kk][tx * 4]);
      float ar[4] = {a.x, a.y, a.z, a.w};
      float br[4] = {b.x, b.y, b.z, b.w};
      #pragma unroll
      for (int i = 0; i < 4; ++i)
        #pragma unroll
        for (int j = 0; j < 4; ++j)
          acc[i][j] = fmaf(ar[i], br[j], acc[i][j]);
    }
  }
}

// ---- zero carried state ----
__global__ __launch_bounds__(256) void r9_wszero(float* h0, float* c0, float* Gv,
                                                 float* logp0, float* accum) {
  int idx = blockIdx.x * 256 + threadIdx.x;
  if (idx < RR * HD_) { h0[idx] = 0.f; c0[idx] = 0.f; }
  if (idx < RR) { Gv[idx] = 0.f; logp0[idx] = 0.f; }
  if (idx < 128) accum[idx] = 0.f;
}

__global__ __launch_bounds__(256) void r9_flag(float* dout) {
  int idx = blockIdx.x * 256 + threadIdx.x;
  if (idx < OUT_N) dout[idx] = (idx == 6656) ? 20000.0f : 0.0f;
}

// xfb once
__global__ __launch_bounds__(256) void r9_xfb(const float* __restrict__ xf,
                                              const float* __restrict__ Wih,
                                              const float* __restrict__ bih,
                                              const float* __restrict__ bhh,
                                              float* __restrict__ xfb) {
  __shared__ __align__(16) float As[BKT][LDP];
  __shared__ __align__(16) float Bs[BKT][LDP];
  float acc[4][4] = {};
  int n0 = blockIdx.x * 64;
  r9_gemm(xf, 1024, Wih, 1152, 1024, 0, n0, 1 << 30, acc, As, Bs);
  int tx = threadIdx.x & 15, ty = threadIdx.x >> 4;
  #pragma unroll
  for (int i = 0; i < 4; ++i)
    #pragma unroll
    for (int j = 0; j < 4; ++j) {
      int r = ty * 4 + i, c = n0 + tx * 4 + j;
      xfb[(size_t)r * GD + c] = acc[i][j] + bih[c] + bhh[c];
    }
}

// gates GEMM: 32 rows x 128 cols x 1 gate per block; grid (8, 16, 4) = 512 blocks.
// A rows gathered via parent order; inp operand computed inline (one-hot column gather).
__global__ __launch_bounds__(256) void r9_glstm(
    const float* __restrict__ hprev,
    const float* __restrict__ Whh, const float* __restrict__ Wih,
    const float* __restrict__ Wio, const float* __restrict__ bio,
    const int* __restrict__ s_arr, const int* __restrict__ o_arr, int t,
    float* __restrict__ gates)
{
  __shared__ __align__(16) float As[BKT][AP];
  __shared__ __align__(16) float Bs[BKT][BP];
  float acc[4][4] = {};
  const int tid = threadIdx.x;
  const int c0 = blockIdx.x * 128;        // col offset within gate
  const int r0 = blockIdx.y * 32;
  const int g  = blockIdx.z;
  const int a_r = tid >> 3;               // 0..31
  const int a_k = (tid & 7) * 2;          // 0,2,..,14
  const int b_r = tid >> 1;               // 0..127
  const int b_k = (tid & 1) * 8;          // 0 or 8
  const int tx = tid & 31, ty = tid >> 5; // cols tx*4, rows ty*4
  const int arow = r0 + a_r;
  const int asrc = (t == 0) ? arow : o_arr[(size_t)(t - 1) * RR + arow];
  const int s_row = (t == 0) ? 400 : s_arr[(size_t)(t - 1) * RR + arow];
  const float* Arow  = hprev + (size_t)asrc * HD_;
  const float* BrowW = Whh + (size_t)(g * 1024 + c0 + b_r) * HD_;
  for (int k0 = 0; k0 < HD_; k0 += BKT) {
    float2 av = *reinterpret_cast<const float2*>(Arow + k0 + a_k);
    float4 b0 = *reinterpret_cast<const float4*>(BrowW + k0 + b_k);
    float4 b1 = *reinterpret_cast<const float4*>(BrowW + k0 + b_k + 4);
    __syncthreads();
    As[a_k][a_r] = av.x; As[a_k + 1][a_r] = av.y;
    Bs[b_k + 0][b_r] = b0.x; Bs[b_k + 1][b_r] = b0.y;
    Bs[b_k + 2][b_r] = b0.z; Bs[b_k + 3][b_r] = b0.w;
    Bs[b_k + 4][b_r] = b1.x; Bs[b_k + 5][b_r] = b1.y;
    Bs[b_k + 6][b_r] = b1.z; Bs[b_k + 7][b_r] = b1.w;
    __syncthreads();
    #pragma unroll
    for (int kk = 0; kk < BKT; ++kk) {
      float4 a = *reinterpret_cast<const float4*>(&As[kk][ty * 4]);
      float4 b = *reinterpret_cast<const float4*>(&Bs[kk][tx * 4]);
      float ar[4] = {a.x, a.y, a.z, a.w};
      float br[4] = {b.x, b.y, b.z, b.w};
      #pragma unroll
      for (int i = 0; i < 4; ++i)
        #pragma unroll
        for (int j = 0; j < 4; ++j)
          acc[i][j] = fmaf(ar[i], br[j], acc[i][j]);
    }
  }
  // inp part: K=128; A element = relu(Wio[m*401 + s_row] + bio[m]), rows NOT gathered
  const float* BrowI = Wih + (size_t)(g * 1024 + c0 + b_r) * 1152 + 1024;
  for (int k0 = 0; k0 < 128; k0 += BKT) {
    int m0 = k0 + a_k;
    float a0 = fmaxf(Wio[(size_t)m0 * 401 + s_row] + bio[m0], 0.f);
    float a1 = fmaxf(Wio[(size_t)(m0 + 1) * 401 + s_row] + bio[m0 + 1], 0.f);
    float4 b0 = *reinterpret_cast<const float4*>(BrowI + k0 + b_k);
    float4 b1 = *reinterpret_cast<const float4*>(BrowI + k0 + b_k + 4);
    __syncthreads();
    As[a_k][a_r] = a0; As[a_k + 1][a_r] = a1;
    Bs[b_k + 0][b_r] = b0.x; Bs[b_k + 1][b_r] = b0.y;
    Bs[b_k + 2][b_r] = b0.z; Bs[b_k + 3][b_r] = b0.w;
    Bs[b_k + 4][b_r] = b1.x; Bs[b_k + 5][b_r] = b1.y;
    Bs[b_k + 6][b_r] = b1.z; Bs[b_k + 7][b_r] = b1.w;
    __syncthreads();
    #pragma unroll
    for (int kk = 0; kk < BKT; ++kk) {
      float4 a = *reinterpret_cast<const float4*>(&As[kk][ty * 4]);
      float4 b = *reinterpret_cast<const float4*>(&Bs[kk][tx * 4]);
      float ar[4] = {a.x, a.y, a.z, a.w};
      float br[4] = {b.x, b.y, b.z, b.w};
      #pragma unroll
      for (int i = 0; i < 4; ++i)
        #pragma unroll
        for (int j = 0; j < 4; ++j)
          acc[i][j] = fmaf(ar[i], br[j], acc[i][j]);
    }
  }
  #pragma unroll
  for (int i = 0; i < 4; ++i)
    #pragma unroll
    for (int j = 0; j < 4; ++j)
      gates[(size_t)(r0 + ty * 4 + i) * GD + g * 1024 + c0 + tx * 4 + j] = acc[i][j];
}

// LSTM pointwise: + xfb, gathered c_prev
__global__ __launch_bounds__(256) void r9_lstm(const float* gates, const float* xfb,
                                               const float* cprev, const int* o_arr, int t,
                                               float* cout, float* hout) {
  int idx = blockIdx.x * 256 + threadIdx.x;   // 512*1024
  int r = idx >> 10, n = idx & 1023;
  int src = (t == 0) ? r : o_arr[(size_t)(t - 1) * RR + r];
  const float* g = gates + (size_t)r * GD;
  const float* xb = xfb + (size_t)(r & 63) * GD;
  float gi = g[n] + xb[n];
  float gf = g[1024 + n] + xb[1024 + n];
  float gg = g[2048 + n] + xb[2048 + n];
  float go = g[3072 + n] + xb[3072 + n];
  float cp = cprev[(size_t)src * HD_ + n];
  float c = r9_sigm(gf) * cp + r9_sigm(gi) * tanhf(gg);
  cout[idx] = c;
  hout[idx] = r9_sigm(go) * tanhf(c);
}

// fc1 K-split: grid (16,8,2); partial -> hdp[z]
__global__ __launch_bounds__(256) void r9_fc1(const float* h, const float* W1, float* hdp) {
  __shared__ __align__(16) float As[BKT][LDP];
  __shared__ __align__(16) float Bs[BKT][LDP];
  float acc[4][4] = {};
  int n0 = blockIdx.x * 64, r0 = blockIdx.y * 64, z = blockIdx.z;
  r9_gemm(h + z * 512, HD_, W1 + z * 512, HD_, 512, r0, n0, 1 << 30, acc, As, Bs);
  float* dst = hdp + (size_t)z * RR * HD_;
  int tx = threadIdx.x & 15, ty = threadIdx.x >> 4;
  #pragma unroll
  for (int i = 0; i < 4; ++i)
    #pragma unroll
    for (int j = 0; j < 4; ++j)
      dst[(size_t)(r0 + ty * 4 + i) * HD_ + n0 + tx * 4 + j] = acc[i][j];
}

// combine fc1 partials + bias + relu
__global__ __launch_bounds__(256) void r9_fc1c(const float* hdp, const float* b1, float* hd) {
  int idx = blockIdx.x * 256 + threadIdx.x;   // 524288
  hd[idx] = fmaxf(hdp[idx] + hdp[RR * HD_ + idx] + b1[idx & 1023], 0.f);
}

// out K-split: grid (7,8,4); partial -> outp[z]
__global__ __launch_bounds__(256) void r9_out(const float* hd, const float* Wo, float* outp) {
  __shared__ __align__(16) float As[BKT][LDP];
  __shared__ __align__(16) float Bs[BKT][LDP];
  float acc[4][4] = {};
  int n0 = blockIdx.x * 64, r0 = blockIdx.y * 64, z = blockIdx.z;
  r9_gemm(hd + z * 256, HD_, Wo + z * 256, HD_, 256, r0, n0, VV, acc, As, Bs);
  float* dst = outp + (size_t)z * RR * VV;
  int tx = threadIdx.x & 15, ty = threadIdx.x >> 4;
  #pragma unroll
  for (int i = 0; i < 4; ++i)
    #pragma unroll
    for (int j = 0; j < 4; ++j) {
      int c = n0 + tx * 4 + j;
      if (c < VV) dst[(size_t)(r0 + ty * 4 + i) * VV + c] = acc[i][j];
    }
}

// per-row: combine logit partials + bias, log_softmax, entropy, gumbel-with-max
__global__ __launch_bounds__(256) void r9_soft(const float* outp, const float* bo,
                                               const float* logp_in, const float* Gv,
                                               const float* gum, float* lp, float* gb,
                                               float* entold) {
  __shared__ float red[4];
  int r = blockIdx.x, tid = threadIdx.x;
  bool v1 = (tid + 256) < VV;
  size_t off0 = (size_t)r * VV + tid;
  float l0 = outp[off0] + outp[RR * VV + off0] + outp[2 * RR * VV + off0]
           + outp[3 * RR * VV + off0] + bo[tid];
  float l1 = -INFINITY;
  if (v1) {
    size_t off1 = off0 + 256;
    l1 = outp[off1] + outp[RR * VV + off1] + outp[2 * RR * VV + off1]
       + outp[3 * RR * VV + off1] + bo[tid + 256];
  }
  float m = r9_bmax256(fmaxf(l0, l1), red);
  float e0 = expf(l0 - m), e1 = v1 ? expf(l1 - m) : 0.f;
  float s = r9_bsum256(e0 + e1, red);
  float ls = logf(s);
  float lp0 = l0 - m - ls, lp1 = l1 - m - ls;
  float ent = lp0 * expf(lp0) + (v1 ? lp1 * expf(lp1) : 0.f);
  ent = r9_bsum256(ent, red);
  if (tid == 0) entold[r] = ent;
  float lpr = logp_in[r];
  const float* ur = gum + (size_t)r * VV;
  float gp0, gp1 = -INFINITY;
  { float u = ur[tid];
    gp0 = lp0 + lpr - logf(-logf(u * (1.f - 2e-7f) + 1e-7f)); }
  if (v1) { float u = ur[tid + 256];
            gp1 = lp1 + lpr - logf(-logf(u * (1.f - 2e-7f) + 1e-7f)); }
  float Z = r9_bmax256(fmaxf(gp0, gp1), red);
  float T = Gv[r];
  int i = r & 63, j = r >> 6;
  float* gbr = gb + (size_t)i * (KB_ * VV) + j * VV;
  {
    float vv = T - gp0 + r9_log1mexp(gp0 - Z);
    gbr[tid] = T - fmaxf(vv, 0.f) - log1pf(expf(-fabsf(vv)));
    lp[(size_t)r * VV + tid] = lp0;
  }
  if (v1) {
    float vv = T - gp1 + r9_log1mexp(gp1 - Z);
    gbr[tid + 256] = T - fmaxf(vv, 0.f) - log1pf(expf(-fabsf(vv)));
    lp[(size_t)r * VV + tid + 256] = lp1;
  }
}

// pack (value, index) so u64-max == (max value, tie -> lower index)
__device__ __forceinline__ unsigned long long r9_pack(float v, int c) {
  unsigned u = __float_as_uint(v);
  u = (u & 0x80000000u) ? ~u : (u | 0x80000000u);
  return ((unsigned long long)u << 32) | (unsigned)(0xFFFFFFFFu - (unsigned)c);
}

// per-batch top-8: LDS u64 keys + wave shuffle reduce; sel folded in
__global__ __launch_bounds__(256) void r9_topk(const float* gb, int t, float* Gv,
                                               int* s_t, int* o_t, const float* lp,
                                               const float* logp_in, float* logp_out,
                                               const float* entold, float* entbm,
                                               float* lv_t) {
  __shared__ unsigned long long keys[KB_ * VV];
  __shared__ unsigned long long wbest[4];
  __shared__ unsigned long long selK[KB_];
  int i = blockIdx.x, tid = threadIdx.x;
  int lane = tid & 63, wid = tid >> 6;
  int limit = (t == 0) ? VV : KB_ * VV;
  for (int c = tid; c < limit; c += 256)
    keys[c] = r9_pack(gb[(size_t)i * (KB_ * VV) + c], c);
  __syncthreads();
  for (int it = 0; it < KB_; ++it) {
    unsigned long long b = 0ull;
    for (int c = tid; c < limit; c += 256) {
      unsigned long long k = keys[c];
      b = (k > b) ? k : b;
    }
    #pragma unroll
    for (int o = 32; o; o >>= 1) {
      unsigned long long x = __shfl_xor(b, o, 64);
      b = (x > b) ? x : b;
    }
    if (lane == 0) wbest[wid] = b;
    __syncthreads();
    unsigned long long g = wbest[0];
    g = (wbest[1] > g) ? wbest[1] : g;
    g = (wbest[2] > g) ? wbest[2] : g;
    g = (wbest[3] > g) ? wbest[3] : g;
    if (tid == 0) {
      int csel = (int)(0xFFFFFFFFu - (unsigned)(g & 0xFFFFFFFFu));
      keys[csel] = 0ull;
      selK[it] = g;
    }
    __syncthreads();
  }
  if (tid < KB_) {
    unsigned long long g = selK[tid];
    unsigned x = (unsigned)(g >> 32);
    x = (x & 0x80000000u) ? (x & 0x7FFFFFFFu) : ~x;
    float v = __uint_as_float(x);
    int c = (int)(0xFFFFFFFFu - (unsigned)(g & 0xFFFFFFFFu));
    int r = tid * 64 + i;
    int s = c % VV;
    int o = (c / VV) * 64 + i;
    Gv[r] = v;
    s_t[r] = s;
    o_t[r] = o;
    float lv = lp[(size_t)o * VV + s];
    logp_out[r] = logp_in[o] + lv;
    entbm[r] = entold[o];
    lv_t[r] = lv;
  }
}

// compute_log_R per batch: 37 logsumexps distributed over 4 waves (shuffle-only)
__global__ __launch_bounds__(256) void r9_logR(const float* logp_new, const float* entbm,
                                               float* accum, float* dout, int last) {
  __shared__ float Tm[KB_][NPTS];
  __shared__ float base[NPTS];
  __shared__ float phi[KB_], pj[KB_];
  __shared__ float res[37];
  int i = blockIdx.x, tid = threadIdx.x;
  int lane = tid & 63, wid = tid >> 6;
  if (tid < KB_) { float ph = logp_new[tid * 64 + i]; phi[tid] = ph; pj[tid] = expf(ph); }
  __syncthreads();
  float pS = ((pj[0] + pj[1]) + (pj[2] + pj[3])) + ((pj[4] + pj[5]) + (pj[6] + pj[7]));
  for (int n = tid; n < NPTS; n += 256) {
    float lu = logf((n + 0.5f) * (1.0f / NPTS));
    float b = -pS * lu;
    #pragma unroll
    for (int j = 0; j < KB_; ++j) {
      float tv = r9_log1mexp(pj[j] * lu);
      Tm[j][n] = tv; b += tv;
    }
    base[n] = b;
  }
  __syncthreads();
  const float logN = 6.9077552789821f;   // log(1000)
  for (int ridx = wid; ridx < 37; ridx += 4) {
    int jj = -1, ll = -1;
    if (ridx >= 1 && ridx < 9) jj = ridx - 1;
    else if (ridx >= 9) { jj = cPJ[ridx - 9]; ll = cPL[ridx - 9]; }
    float mx = -INFINITY;
    for (int n = lane; n < NPTS; n += 64) {
      float v = base[n];
      if (jj >= 0) v -= Tm[jj][n];
      if (ll >= 0) v -= Tm[ll][n];
      mx = fmaxf(mx, v);
    }
    #pragma unroll
    for (int o = 32; o; o >>= 1) mx = fmaxf(mx, __shfl_xor(mx, o, 64));
    float sm = 0.f;
    for (int n = lane; n < NPTS; n += 64) {
      float v = base[n];
      if (jj >= 0) v -= Tm[jj][n];
      if (ll >= 0) v -= Tm[ll][n];
      sm += expf(v - mx);
    }
    #pragma unroll
    for (int o = 32; o; o >>= 1) sm += __shfl_xor(sm, o, 64);
    if (lane == 0) res[ridx] = mx + logf(sm) - logN;
  }
  __syncthreads();
  if (tid == 0) {
    float logI = res[0];
    float Wsum = 0.f, ws = 0.f;
    #pragma unroll
    for (int j = 0; j < KB_; ++j) {
      float lRs = res[1 + j] - logI;
      float wj = expf(phi[j] + lRs);
      Wsum += wj;
      ws += wj * entbm[j * 64 + i];
    }
    accum[i] += ws;               // ent_plot
    accum[64 + i] += ws / Wsum;   // entropy_element
    if (last) {
      for (int j = 0; j < KB_; ++j) {
        dout[13376 + i * 8 + j] = res[1 + j] - logI;     // log_R_s
        dout[17984 + i * 8 + j] = phi[j];                // phi_k
        for (int l = 0; l < KB_; ++l) {
          float v = (l == j) ? 0.f : (res[r9_pidx(j, l)] - res[1 + j]);
          dout[13888 + i * 64 + j * 8 + l] = v;          // log_R_ss
        }
      }
    }
  }
}

// final: walk ancestor chains, pack all outputs (float32)
__global__ __launch_bounds__(512) void r9_final(const float* lv_arr, const int* s_arr,
                                                const int* o_arr, const float* accum,
                                                float* dout) {
  int r = threadIdx.x;
  int i = r & 63, j = r >> 6;
  float vals[LL]; int svs[LL];
  int a = r;
  for (int tt = LL - 1; tt >= 0; --tt) {
    vals[tt] = lv_arr[tt * RR + a];
    svs[tt]  = s_arr[tt * RR + a];
    a = o_arr[tt * RR + a];
  }
  #pragma unroll
  for (int tt = 0; tt < LL; ++tt) {
    dout[i * 104 + j * 13 + tt] = vals[tt];
    dout[6656 + i * 104 + j * 13 + tt] = (float)svs[tt];
  }
  if (r < 64) {
    dout[13312 + r] = accum[64 + r];   // entropy_element
    dout[18496 + r] = accum[r];        // ent_plot
  }
}

extern "C" void kernel_launch(void* const* d_in, const int* in_sizes, int n_in,
                              void* d_out, int out_size, void* d_ws, size_t ws_size,
                              hipStream_t stream) {
  const float* x_feat  = (const float*)d_in[0];
  const float* W_in_op = (const float*)d_in[1];
  const float* b_in_op = (const float*)d_in[2];
  const float* W_ih    = (const float*)d_in[3];
  const float* W_hh    = (const float*)d_in[4];
  const float* b_ih    = (const float*)d_in[5];
  const float* b_hh    = (const float*)d_in[6];
  const float* W_fc1   = (const float*)d_in[7];
  const float* b_fc1   = (const float*)d_in[8];
  const float* W_out   = (const float*)d_in[9];
  const float* b_out   = (const float*)d_in[10];
  const float* gum     = (const float*)d_in[11];
  float* out           = (float*)d_out;

  float* W = (float*)d_ws;
  size_t o = 0;
  float* lv_arr = W + o; o += (size_t)LL * RR;
  float* Gv     = W + o; o += RR;
  float* logpb0 = W + o; o += RR;
  float* logpb1 = W + o; o += RR;
  float* entold = W + o; o += RR;
  float* entbm  = W + o; o += RR;
  float* accum  = W + o; o += 128;
  int* s_arr = (int*)(W + o); o += (size_t)LL * RR;
  int* o_arr = (int*)(W + o); o += (size_t)LL * RR;
  float* xfb    = W + o; o += (size_t)64 * GD;
  float* gates  = W + o; o += (size_t)RR * GD;        // aliased: hdp[2] then outp[4]
  float* lp     = W + o; o += (size_t)RR * VV;
  float* gb     = W + o; o += (size_t)RR * VV;
  float* h2[2]; h2[0] = W + o; o += (size_t)RR * HD_; h2[1] = W + o; o += (size_t)RR * HD_;
  float* c2[2]; c2[0] = W + o; o += (size_t)RR * HD_; c2[1] = W + o; o += (size_t)RR * HD_;
  float* hd     = W + o; o += (size_t)RR * HD_;
  size_t needed_bytes = o * sizeof(float);
  float* logpb[2] = {logpb0, logpb1};
  float* hdp  = gates;            // 2 x RR*HD_  (fc1 partials)
  float* outp = gates;            // 4 x RR*VV   (out partials, after hdp dead)

  if (ws_size < needed_bytes) {
    r9_flag<<<(OUT_N + 255) / 256, 256, 0, stream>>>(out);
    return;
  }

  r9_wszero<<<2048, 256, 0, stream>>>(h2[0], c2[0], Gv, logpb[0], accum);
  r9_xfb<<<64, 256, 0, stream>>>(x_feat, W_ih, b_ih, b_hh, xfb);

  for (int t = 0; t < LL; ++t) {
    int pi = t & 1, po = pi ^ 1;
    r9_glstm<<<dim3(8, 16, 4), 256, 0, stream>>>(h2[pi], W_hh, W_ih, W_in_op, b_in_op,
                                                 s_arr, o_arr, t, gates);
    r9_lstm<<<2048, 256, 0, stream>>>(gates, xfb, c2[pi], o_arr, t, c2[po], h2[po]);
    r9_fc1<<<dim3(16, 8, 2), 256, 0, stream>>>(h2[po], W_fc1, hdp);
    r9_fc1c<<<2048, 256, 0, stream>>>(hdp, b_fc1, hd);
    r9_out<<<dim3(7, 8, 4), 256, 0, stream>>>(hd, W_out, outp);
    r9_soft<<<512, 256, 0, stream>>>(outp, b_out, logpb[pi], Gv,
                                     gum + (size_t)t * RR * VV, lp, gb, entold);
    r9_topk<<<64, 256, 0, stream>>>(gb, t, Gv, s_arr + (size_t)t * RR,
                                    o_arr + (size_t)t * RR, lp, logpb[pi], logpb[po],
                                    entold, entbm, lv_arr + (size_t)t * RR);
    r9_logR<<<64, 256, 0, stream>>>(logpb[po], entbm, accum, out, (t == LL - 1) ? 1 : 0);
  }
  r9_final<<<1, 512, 0, stream>>>(lv_arr, s_arr, o_arr, accum, out);
}